// Round 5
// baseline (342.298 us; speedup 1.0000x reference)
//
#include <hip/hip_runtime.h>

// TemporalDilatedAttention on gfx950 — round 11
// vs R10 (FAILED, absmax 0.125): PH split-K table covered only 256 of the
// 512 K-tiles (16384/32). Fixed: 14 groups = 8x37 + 6x36 = 512 tiles.
// Everything else identical to R10: S and PH on the 256x256 / 8-wave /
// BK=32 quad-buffered counted-vmcnt core (per-wave 128x64 -> 87 FLOP per
// LDS byte vs 32 for the old 64x64 tile, which was the 26%-MfmaUtil
// plateau's root cause). PH partials land in 14 dead 4-MB workspace
// regions; G/FO/wpack keep the R9 128^2 core.

#define DD    1024
#define TALL  16384

typedef _Float16 half8  __attribute__((ext_vector_type(8)));
typedef _Float16 half4v __attribute__((ext_vector_type(4)));
typedef float    floatx4 __attribute__((ext_vector_type(4)));
typedef unsigned int u32;

// ---------------- workspace layout (bytes), ~132.5 MB ----------------
static const size_t OFF_WOT  = 0;          // 2 MB  Wo^T f16
static const size_t OFF_WV16 = 2097152;    // 2 MB  Wv f16
static const size_t OFF_WK16 = 4194304;    // 2 MB  Wk f16
static const size_t OFF_WQ16 = 6291456;    // 2 MB  Wq f16
static const size_t OFF_XB   = 8388608;    // 0.5 MB x f16
static const size_t OFF_G    = 8912896;    // 2 MB  G[h][q][f] f16
static const size_t OFF_WVOT = 11010048;   // 8 MB  WVOT[j][h*1024+k] f16
static const size_t OFF_WQKT = 19398656;   // 8 MB  WQKT[h][f][d] f16
static const size_t OFF_BVWO = 27787264;   // 4 KB  bv@Wo f32
static const size_t OFF_BQK  = 27791360;   // 16 KB bqk[h][f] f32
static const size_t OFF_PHR  = 27807744;   // 2 MB  PHred[q][h*1024+k] f16
static const size_t OFF_OPP  = 29904896;   // 8 MB  FO partials (8 x 256x1024 f32)
static const size_t OFF_HB   = 38293504;   // 32 MB histb (dead after S -> PH chunks)
static const size_t OFF_HT   = 71848960;   // 32 MB hist^T f16 [feat][t]
static const size_t OFF_S    = 105403392;  // 32 MB S/P f16 [h][q][t]

// PH partial chunks: 14 x 4 MB over regions dead during launches 6-7.
// 0-1: weight cvts [0, 8388608)   2-3: WQKT [19398656, 27787264)
// 4-5: OPP [29904896, 38293504)   6-13: histb [38293504, 71847936)
__device__ __forceinline__ size_t chunk_off(int g) {
  if (g < 2) return (size_t)g * 4194304;
  if (g < 4) return 19398656 + (size_t)(g - 2) * 4194304;
  if (g < 6) return 29904896 + (size_t)(g - 4) * 4194304;
  return 38293504 + (size_t)(g - 6) * 4194304;
}

// ---------------- async global->LDS, 16B per lane ----------------
__device__ __forceinline__ void gl_lds16(const void* g, void* l) {
  __builtin_amdgcn_global_load_lds((const __attribute__((address_space(1))) u32*)g,
                                   (__attribute__((address_space(3))) u32*)l, 16, 0, 0);
}

// ---------------- prep (unchanged) ----------------
__global__ void prep_kernel(const float* __restrict__ Wo, const float* __restrict__ Wv,
                            const float* __restrict__ Wk, const float* __restrict__ Wq,
                            const float* __restrict__ x, const float* __restrict__ hist,
                            _Float16* __restrict__ WoT, _Float16* __restrict__ Wv16,
                            _Float16* __restrict__ Wk16, _Float16* __restrict__ Wq16,
                            _Float16* __restrict__ xb, _Float16* __restrict__ histb,
                            _Float16* __restrict__ histT) {
  int bid = blockIdx.x, tid = threadIdx.x;
  if (bid < 1024) {                        // Wo transpose+cvt
    int k0 = (bid & 31) * 32, n0 = (bid >> 5) * 32;
    __shared__ float t32[32][33];
    int tx = tid & 31, ty = tid >> 5;
#pragma unroll
    for (int i = 0; i < 4; i++) {
      int r = ty + i * 8;
      t32[r][tx] = Wo[(size_t)(k0 + r) * DD + n0 + tx];
    }
    __syncthreads();
#pragma unroll
    for (int i = 0; i < 4; i++) {
      int r = ty + i * 8;
      WoT[(size_t)(n0 + r) * DD + k0 + tx] = (_Float16)t32[tx][r];
    }
  } else if (bid < 4352) {                 // plain cvt
    const float* src; _Float16* dst; size_t i;
    if (bid < 2048)      { src = Wv; dst = Wv16; i = (size_t)(bid - 1024) * 256 + tid; }
    else if (bid < 3072) { src = Wk; dst = Wk16; i = (size_t)(bid - 2048) * 256 + tid; }
    else if (bid < 4096) { src = Wq; dst = Wq16; i = (size_t)(bid - 3072) * 256 + tid; }
    else                 { src = x;  dst = xb;   i = (size_t)(bid - 4096) * 256 + tid; }
    float4 v = ((const float4*)src)[i];
    half4v h = {(_Float16)v.x, (_Float16)v.y, (_Float16)v.z, (_Float16)v.w};
    *(half4v*)(dst + 4 * i) = h;
  } else {                                 // hist dual write
    int tb = bid - 4352;
    int t0 = (tb & 255) * 64, f0 = (tb >> 8) * 64;
    __shared__ _Float16 lt[64][72];
    int r = tid >> 2, c0 = (tid & 3) * 16;
    half8 s0, s1;
#pragma unroll
    for (int i = 0; i < 4; i++) {
      float4 v = *(const float4*)&hist[(size_t)(t0 + r) * 1024 + f0 + c0 + i * 4];
      half4v h = {(_Float16)v.x, (_Float16)v.y, (_Float16)v.z, (_Float16)v.w};
      *(half4v*)&lt[r][c0 + i * 4] = h;
      if (i < 2) { s0[i*4]=h[0]; s0[i*4+1]=h[1]; s0[i*4+2]=h[2]; s0[i*4+3]=h[3]; }
      else { s1[(i-2)*4]=h[0]; s1[(i-2)*4+1]=h[1]; s1[(i-2)*4+2]=h[2]; s1[(i-2)*4+3]=h[3]; }
    }
    *(half8*)&histb[(size_t)(t0 + r) * 1024 + f0 + c0] = s0;
    *(half8*)&histb[(size_t)(t0 + r) * 1024 + f0 + c0 + 8] = s1;
    __syncthreads();
    int fr = tid >> 2, tc0 = (tid & 3) * 16;
    half8 o0, o1;
#pragma unroll
    for (int j = 0; j < 8; j++) { o0[j] = lt[tc0 + j][fr]; o1[j] = lt[tc0 + 8 + j][fr]; }
    *(half8*)&histT[(size_t)(f0 + fr) * TALL + t0 + tc0] = o0;
    *(half8*)&histT[(size_t)(f0 + fr) * TALL + t0 + tc0 + 8] = o1;
  }
}

// ---------------- R9 128x128 core (kept for wpack/G/FO) -------------------
__device__ __forceinline__ void gemm_core(const _Float16* __restrict__ A, size_t lda,
                                          const _Float16* __restrict__ B, size_t ldb,
                                          int kIters, _Float16* As, _Float16* Bs,
                                          int tid, floatx4 acc[4][4]) {
  int lane = tid & 63, w = tid >> 6;
  int l15 = lane & 15, quad = lane >> 4;
  int wm = (w >> 1) * 64, wn = (w & 1) * 64;
  int swz = ((tid & 3) ^ ((tid >> 3) & 3)) * 8;
  int pch = (quad ^ ((l15 >> 1) & 3)) * 8;
  const char* gA0 = (const char*)(A + (size_t)(tid >> 2) * lda + swz);
  const char* gA1 = (const char*)(A + ((size_t)(tid >> 2) + 64) * lda + swz);
  const char* gB0 = (const char*)(B + (size_t)(tid >> 2) * ldb + swz);
  const char* gB1 = (const char*)(B + ((size_t)(tid >> 2) + 64) * ldb + swz);
  _Float16* lA = As + w * 512;
  _Float16* lB = Bs + w * 512;
#define GC_STAGE(buf, k)                                    \
  do {                                                      \
    size_t off_ = (size_t)(k) * 64;                         \
    gl_lds16(gA0 + off_, lA + (buf) * 4096);                \
    gl_lds16(gA1 + off_, lA + (buf) * 4096 + 2048);         \
    gl_lds16(gB0 + off_, lB + (buf) * 4096);                \
    gl_lds16(gB1 + off_, lB + (buf) * 4096 + 2048);         \
  } while (0)
#define GC_STEP(buf, k)                                                       \
  do {                                                                        \
    if ((k) + 1 < kIters) asm volatile("s_waitcnt vmcnt(4)" ::: "memory");    \
    else                  asm volatile("s_waitcnt vmcnt(0)" ::: "memory");    \
    asm volatile("s_barrier" ::: "memory");                                   \
    const _Float16* Ac_ = As + (buf) * 4096;                                  \
    const _Float16* Bc_ = Bs + (buf) * 4096;                                  \
    half8 a_[4];                                                              \
    _Pragma("unroll")                                                         \
    for (int mi = 0; mi < 4; mi++)                                            \
      a_[mi] = *(const half8*)&Ac_[(wm + mi * 16 + l15) * 32 + pch];          \
    _Pragma("unroll")                                                         \
    for (int ni = 0; ni < 4; ni++) {                                          \
      half8 b8_ = *(const half8*)&Bc_[(wn + ni * 16 + l15) * 32 + pch];       \
      _Pragma("unroll")                                                       \
      for (int mi = 0; mi < 4; mi++)                                          \
        acc[mi][ni] = __builtin_amdgcn_mfma_f32_16x16x32_f16(a_[mi], b8_,     \
                                                             acc[mi][ni], 0, 0, 0); \
    }                                                                         \
    asm volatile("s_waitcnt lgkmcnt(0)" ::: "memory");                        \
    asm volatile("s_barrier" ::: "memory");                                   \
    if ((k) + 2 < kIters) GC_STAGE(buf, (k) + 2);                             \
  } while (0)
  GC_STAGE(0, 0);
  GC_STAGE(1, 1);
  for (int kk = 0; kk < kIters; kk += 2) {
    GC_STEP(0, kk);
    GC_STEP(1, kk + 1);
  }
#undef GC_STEP
#undef GC_STAGE
}

// ---------------- 256x256 8-wave BK=32 quad-buffered core -----------------
// LDS: As/Bs = [4 bufs][256 rows][32 f16] (8192 f16 per buf) = 64 KB each.
// Per K-tile: 4 gl_lds16/thread stages, 12 ds_read_b128 per wave, 32 MFMA
// per wave (2 phases of 4mi x 4ni). Pipeline depth 2: stage(t+2) issued at
// tile t; vmcnt(4) at tile entry retires tile t's stages while t+1's 4 stay
// in flight. ONE barrier per tile. Tail lgkmcnt(0) fences this wave's
// ds_reads of buf t before barrier t+1 (re-stage of that buf is at t+2, two
// barriers later). Swizzle: global chunk pre-swizzled at stage (LDS dest
// linear); reads use pch = (quad ^ ((l15>>1)&3))*8 — same involution.
__device__ __forceinline__ void gemm256_core(const _Float16* __restrict__ A, size_t lda,
                                             const _Float16* __restrict__ B, size_t ldb,
                                             int nT, _Float16* As, _Float16* Bs,
                                             int tid, floatx4 acc[8][4]) {
  int lane = tid & 63, w = tid >> 6;
  int l15 = lane & 15, quad = lane >> 4;
  int wr = w >> 2, wc = w & 3;             // wave grid 2 (M) x 4 (N)
  int pch = (quad ^ ((l15 >> 1) & 3)) * 8;
  int srow = tid >> 2;                      // 0..127 (round 0 rows)
  int schunk = (tid & 3) ^ ((tid >> 3) & 3);
  const char* gA0 = (const char*)(A + (size_t)srow * lda + schunk * 8);
  const char* gA1 = (const char*)(A + (size_t)(srow + 128) * lda + schunk * 8);
  const char* gB0 = (const char*)(B + (size_t)srow * ldb + schunk * 8);
  const char* gB1 = (const char*)(B + (size_t)(srow + 128) * ldb + schunk * 8);
  _Float16* lA = As + w * 512;              // wave's 1-KB segment per round
  _Float16* lB = Bs + w * 512;
#define ST256(buf, t)                                         \
  do { size_t o_ = (size_t)(t) * 64;                          \
    gl_lds16(gA0 + o_, lA + (buf) * 8192);                    \
    gl_lds16(gA1 + o_, lA + (buf) * 8192 + 4096);             \
    gl_lds16(gB0 + o_, lB + (buf) * 8192);                    \
    gl_lds16(gB1 + o_, lB + (buf) * 8192 + 4096);             \
  } while (0)
  ST256(0, 0);
  ST256(1, 1);
  for (int t = 0; t < nT; ++t) {
    int buf = t & 3;
    if (t + 1 < nT) asm volatile("s_waitcnt vmcnt(4)" ::: "memory");
    else            asm volatile("s_waitcnt vmcnt(0)" ::: "memory");
    asm volatile("s_barrier" ::: "memory");
    if (t + 2 < nT) ST256((t + 2) & 3, t + 2);
    const _Float16* Ac = As + buf * 8192;
    const _Float16* Bc = Bs + buf * 8192;
    half8 b8[4];
#pragma unroll
    for (int ni = 0; ni < 4; ni++)
      b8[ni] = *(const half8*)&Bc[(wc * 64 + ni * 16 + l15) * 32 + pch];
    half8 a8[4];
#pragma unroll
    for (int mi = 0; mi < 4; mi++)
      a8[mi] = *(const half8*)&Ac[(wr * 128 + mi * 16 + l15) * 32 + pch];
    __builtin_amdgcn_s_setprio(1);
#pragma unroll
    for (int mi = 0; mi < 4; mi++)
#pragma unroll
      for (int ni = 0; ni < 4; ni++)
        acc[mi][ni] = __builtin_amdgcn_mfma_f32_16x16x32_f16(a8[mi], b8[ni], acc[mi][ni], 0, 0, 0);
    __builtin_amdgcn_s_setprio(0);
#pragma unroll
    for (int mi = 0; mi < 4; mi++)
      a8[mi] = *(const half8*)&Ac[(wr * 128 + 64 + mi * 16 + l15) * 32 + pch];
    __builtin_amdgcn_s_setprio(1);
#pragma unroll
    for (int mi = 0; mi < 4; mi++)
#pragma unroll
      for (int ni = 0; ni < 4; ni++)
        acc[4 + mi][ni] = __builtin_amdgcn_mfma_f32_16x16x32_f16(a8[mi], b8[ni], acc[4 + mi][ni], 0, 0, 0);
    __builtin_amdgcn_s_setprio(0);
    asm volatile("s_waitcnt lgkmcnt(0)" ::: "memory");
  }
#undef ST256
}

// ---------------- generic single-B GEMM (R9 core) ----------------
template <bool OUTF32>
__launch_bounds__(256, 3)
__global__ void gemm_f16_kernel(const _Float16* __restrict__ A, size_t lda, size_t aoffz,
                                const _Float16* __restrict__ B, size_t ldb, size_t boffz,
                                int kIters, const float* __restrict__ bias, size_t biasoffz,
                                float scale, void* __restrict__ C, size_t ldc, size_t coffz) {
  __shared__ __align__(16) _Float16 As[8192];
  __shared__ __align__(16) _Float16 Bs[8192];
  int tid = threadIdx.x;
  const _Float16* Ab = A + aoffz * blockIdx.z + (size_t)(blockIdx.y * 128) * lda;
  const _Float16* Bb = B + boffz * blockIdx.z + (size_t)(blockIdx.x * 128) * ldb;
  floatx4 acc[4][4];
  floatx4 zero = {0.f, 0.f, 0.f, 0.f};
#pragma unroll
  for (int a = 0; a < 4; a++)
#pragma unroll
    for (int b = 0; b < 4; b++) acc[a][b] = zero;
  gemm_core(Ab, lda, Bb, ldb, kIters, As, Bs, tid, acc);
  int lane = tid & 63, w = tid >> 6;
  int l15 = lane & 15, quad = lane >> 4;
  int wm = (w >> 1) * 64, wn = (w & 1) * 64;
#pragma unroll
  for (int mi = 0; mi < 4; mi++)
#pragma unroll
    for (int ni = 0; ni < 4; ni++) {
      int colg = blockIdx.x * 128 + wn + ni * 16 + l15;
      float bv = bias ? bias[biasoffz * blockIdx.z + colg] : 0.f;
#pragma unroll
      for (int r = 0; r < 4; r++) {
        int rowg = blockIdx.y * 128 + wm + mi * 16 + quad * 4 + r;
        float v = (acc[mi][ni][r] + bv) * scale;
        size_t idx = coffz * blockIdx.z + (size_t)rowg * ldc + colg;
        if (OUTF32) ((float*)C)[idx] = v;
        else ((_Float16*)C)[idx] = (_Float16)v;
      }
    }
}

// ---------------- wpack (unchanged, R9 core) ----------------
__launch_bounds__(256, 3)
__global__ void wpack_kernel(const _Float16* __restrict__ WoT, const _Float16* __restrict__ Wv16,
                             const _Float16* __restrict__ Wk16, const _Float16* __restrict__ Wq16,
                             const float* __restrict__ bv, const float* __restrict__ bq,
                             _Float16* __restrict__ WVOT, _Float16* __restrict__ WQKT,
                             float* __restrict__ bvwo, float* __restrict__ bqk) {
  __shared__ __align__(16) _Float16 As[8192];
  __shared__ __align__(16) _Float16 Bs[8192];
  int bid = blockIdx.x, tid = threadIdx.x;
  if (bid < 512) {
    bool isQK = bid >= 256;
    int g = bid & 255;
    int x = g & 7, y = (g >> 3) & 7, z = g >> 6;
    const _Float16* A = isQK ? Wk16 : WoT;
    const _Float16* B = isQK ? Wq16 : Wv16;
    const _Float16* Ab = A + 256 * z + (size_t)(y * 128) * 1024;
    const _Float16* Bb = B + 256 * z + (size_t)(x * 128) * 1024;
    floatx4 acc[4][4];
    floatx4 zero = {0.f, 0.f, 0.f, 0.f};
#pragma unroll
    for (int a = 0; a < 4; a++)
#pragma unroll
      for (int b = 0; b < 4; b++) acc[a][b] = zero;
    gemm_core(Ab, 1024, Bb, 1024, 8, As, Bs, tid, acc);
    float scale = isQK ? 0.0625f : 1.0f;
    _Float16* C = isQK ? WQKT : WVOT;
    size_t ldc = isQK ? 1024 : 4096;
    size_t zoff = isQK ? (size_t)1048576 * z : (size_t)1024 * z;
    int lane = tid & 63, w = tid >> 6;
    int l15 = lane & 15, quad = lane >> 4;
    int wm = (w >> 1) * 64, wn = (w & 1) * 64;
#pragma unroll
    for (int mi = 0; mi < 4; mi++)
#pragma unroll
      for (int ni = 0; ni < 4; ni++) {
        int col = x * 128 + wn + ni * 16 + l15;
#pragma unroll
        for (int r = 0; r < 4; r++) {
          int row = y * 128 + wm + mi * 16 + quad * 4 + r;
          C[zoff + (size_t)row * ldc + col] = (_Float16)(acc[mi][ni][r] * scale);
        }
      }
  } else if (bid < 516) {
    int j = (bid - 512) * 256 + tid;
    const half8* row = (const half8*)(WoT + (size_t)j * 1024);
    float a = 0.f;
    for (int c = 0; c < 128; c++) {
      half8 w8 = row[c];
#pragma unroll
      for (int e = 0; e < 8; e++) a += bv[c * 8 + e] * (float)w8[e];
    }
    bvwo[j] = a;
  } else {
    int idx = (bid - 516) * 256 + tid;
    int h = idx >> 10, f = idx & 1023;
    const _Float16* row = Wk16 + (size_t)f * 1024 + h * 256;
    float a = 0.f;
    for (int n = 0; n < 256; n++) a += bq[h * 256 + n] * (float)row[n];
    bqk[idx] = a * 0.0625f;
  }
}

// ---------------- S gemm: 256^2 core, 256 blocks (1/CU) -------------------
// bid = h*64 + nt: the 4 h-sharers of a histb nt-strip differ by 64 = 0 mod 8
// -> same XCD L2.
__launch_bounds__(512, 2)
__global__ void gemm256_s_kernel(const _Float16* __restrict__ G, const _Float16* __restrict__ histb,
                                 _Float16* __restrict__ S) {
  __shared__ __align__(16) _Float16 As[32768];
  __shared__ __align__(16) _Float16 Bs[32768];
  int bid = blockIdx.x, tid = threadIdx.x;
  int h = bid >> 6, nt = bid & 63;
  const _Float16* Ab = G + (size_t)h * 262144;
  const _Float16* Bb = histb + (size_t)(nt * 256) * 1024;
  floatx4 acc[8][4];
  floatx4 zero = {0.f, 0.f, 0.f, 0.f};
#pragma unroll
  for (int a = 0; a < 8; a++)
#pragma unroll
    for (int b = 0; b < 4; b++) acc[a][b] = zero;
  gemm256_core(Ab, 1024, Bb, 1024, 32, As, Bs, tid, acc);
  int lane = tid & 63, w = tid >> 6;
  int l15 = lane & 15, quad = lane >> 4;
  int wr = w >> 2, wc = w & 3;
#pragma unroll
  for (int mh = 0; mh < 2; mh++)
#pragma unroll
    for (int mi = 0; mi < 4; mi++)
#pragma unroll
      for (int ni = 0; ni < 4; ni++) {
        int col = nt * 256 + wc * 64 + ni * 16 + l15;
#pragma unroll
        for (int r = 0; r < 4; r++) {
          int row = wr * 128 + mh * 64 + mi * 16 + quad * 4 + r;
          S[(size_t)h * 4194304 + (size_t)row * TALL + col] = (_Float16)acc[mh * 4 + mi][ni][r];
        }
      }
}

// ---------------- softmax (unchanged) -------------------------------------
__global__ void softmax_kernel(_Float16* __restrict__ S, const float* __restrict__ dil_w) {
  int r = blockIdx.x, tid = threadIdx.x;
  _Float16* row = S + (size_t)r * TALL;
  int lane = tid & 63;
  float ef[8][8];
  float es[8];
  __shared__ float Zf[64];
  __shared__ float Zd[4];
  __shared__ float cf[64];
#pragma unroll
  for (int i = 0; i < 8; i++) {
    half8 v = *(const half8*)&row[((size_t)i * 256 + tid) * 8];
    float s = 0.f;
#pragma unroll
    for (int j = 0; j < 8; j++) { float e = __expf((float)v[j]); ef[i][j] = e; s += e; }
#pragma unroll
    for (int off = 1; off <= 16; off <<= 1) s += __shfl_xor(s, off, 64);
    es[i] = s;
  }
  if ((lane & 31) == 0) {
    int half = tid >> 5;
#pragma unroll
    for (int i = 0; i < 8; i++) Zf[i * 8 + half] = es[i];
  }
  __syncthreads();
  if (tid < 4) {
    int step = 1 << (tid + (tid ? 1 : 0));   // 1,4,8,16
    float z = 0.f;
    for (int f = 0; f < 64; f += step) z += Zf[f];
    Zd[tid] = z;
  }
  __syncthreads();
  if (tid < 64) {
    float w0 = dil_w[0], w1 = dil_w[1], w2 = dil_w[2], w3 = dil_w[3];
    float wmx = fmaxf(fmaxf(w0, w1), fmaxf(w2, w3));
    float e0 = __expf(w0 - wmx), e1 = __expf(w1 - wmx), e2 = __expf(w2 - wmx), e3 = __expf(w3 - wmx);
    float wsum = e0 + e1 + e2 + e3;
    float c = (e0 / wsum) / Zd[0];
    if ((tid & 3) == 0) c += (e1 / wsum) / Zd[1];
    if ((tid & 7) == 0) c += (e2 / wsum) / Zd[2];
    if ((tid & 15) == 0) c += (e3 / wsum) / Zd[3];
    cf[tid] = c * 256.0f;   // x256 keeps P normal in f16; /256 folded into FO
  }
  __syncthreads();
#pragma unroll
  for (int i = 0; i < 8; i++) {
    float c = cf[i * 8 + (tid >> 5)];
    half8 o;
#pragma unroll
    for (int j = 0; j < 8; j++) o[j] = (_Float16)(ef[i][j] * c);
    *(half8*)&row[((size_t)i * 256 + tid) * 8] = o;
  }
}

// ---------------- PH gemm: 256^2 core, split-14, 224 blocks ---------------
// bid = g*16 + h*4 + nt. 512 K-tiles (16384/32) over 14 groups:
// g<8: tiles [g*37, g*37+37)   g>=8: tiles [296+(g-8)*36, +36).
// 8*37 + 6*36 = 296 + 216 = 512.  (R10 BUG: table summed to 256 -> half K.)
__launch_bounds__(512, 2)
__global__ void gemm256_ph_kernel(const _Float16* __restrict__ P, const _Float16* __restrict__ histT,
                                  char* __restrict__ ws) {
  __shared__ __align__(16) _Float16 As[32768];
  __shared__ __align__(16) _Float16 Bs[32768];
  int bid = blockIdx.x, tid = threadIdx.x;
  int g = bid >> 4, hn = bid & 15;
  int h = hn >> 2, nt = hn & 3;
  int start, nT;
  if (g < 8) { start = g * 37; nT = 37; }
  else       { start = 296 + (g - 8) * 36; nT = 36; }
  const _Float16* Ab = P + (size_t)h * 4194304 + (size_t)start * 32;
  const _Float16* Bb = histT + (size_t)(nt * 256) * TALL + (size_t)start * 32;
  floatx4 acc[8][4];
  floatx4 zero = {0.f, 0.f, 0.f, 0.f};
#pragma unroll
  for (int a = 0; a < 8; a++)
#pragma unroll
    for (int b = 0; b < 4; b++) acc[a][b] = zero;
  gemm256_core(Ab, TALL, Bb, TALL, nT, As, Bs, tid, acc);
  float* chunk = (float*)(ws + chunk_off(g));
  int lane = tid & 63, w = tid >> 6;
  int l15 = lane & 15, quad = lane >> 4;
  int wr = w >> 2, wc = w & 3;
#pragma unroll
  for (int mh = 0; mh < 2; mh++)
#pragma unroll
    for (int mi = 0; mi < 4; mi++)
#pragma unroll
      for (int ni = 0; ni < 4; ni++) {
        int col = h * 1024 + nt * 256 + wc * 64 + ni * 16 + l15;
#pragma unroll
        for (int r = 0; r < 4; r++) {
          int row = wr * 128 + mh * 64 + mi * 16 + quad * 4 + r;
          chunk[(size_t)row * 4096 + col] = acc[mh * 4 + mi][ni][r];
        }
      }
}

// ---------------- reduce 14 PH chunks -> PHred[q][h*1024+k] f16 -----------
__global__ void reduce_ph_kernel(const char* __restrict__ ws, _Float16* __restrict__ PHred) {
  size_t e4 = ((size_t)blockIdx.x * 256 + threadIdx.x) * 4;
  float4 s = {0.f, 0.f, 0.f, 0.f};
#pragma unroll
  for (int g = 0; g < 14; g++) {
    const float* p = (const float*)(ws + chunk_off(g));
    float4 v = *(const float4*)&p[e4];
    s.x += v.x; s.y += v.y; s.z += v.z; s.w += v.w;
  }
  half4v o = {(_Float16)s.x, (_Float16)s.y, (_Float16)s.z, (_Float16)s.w};
  *(half4v*)&PHred[e4] = o;
}

// ---------------- FO 8-way reduce + bo + bv@Wo + residual + layernorm ------
__global__ void ln_kernel(const float* __restrict__ x, const float* __restrict__ part2,
                          const float* __restrict__ bo, const float* __restrict__ bvwo,
                          const float* __restrict__ gamma, const float* __restrict__ beta,
                          float* __restrict__ out) {
  int b = blockIdx.x, t = threadIdx.x;
  __shared__ float red[8];
  float y[4];
  float sum = 0.f, sq = 0.f;
#pragma unroll
  for (int i = 0; i < 4; i++) {
    int j = t + i * 256;
    float v = x[(size_t)b * 1024 + j] + bo[j] + bvwo[j];
#pragma unroll
    for (int z = 0; z < 8; z++) v += part2[(size_t)z * 262144 + (size_t)b * 1024 + j];
    y[i] = v;
    sum += v;
    sq += v * v;
  }
#pragma unroll
  for (int off = 1; off < 64; off <<= 1) {
    sum += __shfl_xor(sum, off, 64);
    sq += __shfl_xor(sq, off, 64);
  }
  int w = t >> 6, lane = t & 63;
  if (lane == 0) { red[w] = sum; red[4 + w] = sq; }
  __syncthreads();
  sum = red[0] + red[1] + red[2] + red[3];
  sq = red[4] + red[5] + red[6] + red[7];
  float mu = sum * (1.f / 1024.f);
  float var = sq * (1.f / 1024.f) - mu * mu;
  float inv = rsqrtf(var + 1e-5f);
#pragma unroll
  for (int i = 0; i < 4; i++) {
    int j = t + i * 256;
    out[(size_t)b * 1024 + j] = (y[i] - mu) * inv * gamma[j] + beta[j];
  }
}

// ---------------- host launch ----------------
extern "C" void kernel_launch(void* const* d_in, const int* in_sizes, int n_in,
                              void* d_out, int out_size, void* d_ws, size_t ws_size,
                              hipStream_t stream) {
  const float* x     = (const float*)d_in[0];
  const float* hist  = (const float*)d_in[1];
  const float* Wq    = (const float*)d_in[2];
  const float* bq    = (const float*)d_in[3];
  const float* Wk    = (const float*)d_in[4];
  // bk (d_in[5]) dropped exactly: softmax shift invariance.
  const float* Wv    = (const float*)d_in[6];
  const float* bv    = (const float*)d_in[7];
  const float* Wo    = (const float*)d_in[8];
  const float* bo    = (const float*)d_in[9];
  const float* dil_w = (const float*)d_in[10];
  const float* gamma = (const float*)d_in[11];
  const float* beta  = (const float*)d_in[12];
  char* ws = (char*)d_ws;

  _Float16* WoT   = (_Float16*)(ws + OFF_WOT);
  _Float16* Wv16  = (_Float16*)(ws + OFF_WV16);
  _Float16* Wk16  = (_Float16*)(ws + OFF_WK16);
  _Float16* Wq16  = (_Float16*)(ws + OFF_WQ16);
  _Float16* xb    = (_Float16*)(ws + OFF_XB);
  _Float16* G     = (_Float16*)(ws + OFF_G);
  _Float16* WVOT  = (_Float16*)(ws + OFF_WVOT);
  _Float16* WQKT  = (_Float16*)(ws + OFF_WQKT);
  float* bvwo     = (float*)(ws + OFF_BVWO);
  float* bqk      = (float*)(ws + OFF_BQK);
  _Float16* PHred = (_Float16*)(ws + OFF_PHR);
  float* oppart   = (float*)(ws + OFF_OPP);
  _Float16* histb = (_Float16*)(ws + OFF_HB);
  _Float16* histT = (_Float16*)(ws + OFF_HT);
  _Float16* Sb    = (_Float16*)(ws + OFF_S);

  // 1) prep: WoT, Wv/Wk/Wq/x cvt, hist -> histb + histT (single hist read)
  prep_kernel<<<dim3(8448), 256, 0, stream>>>(Wo, Wv, Wk, Wq, x, hist,
                                              WoT, Wv16, Wk16, Wq16, xb, histb, histT);
  // 2) wpack: WVOT + WQKT + bvwo + bqk in one launch
  wpack_kernel<<<dim3(532), 256, 0, stream>>>(WoT, Wv16, Wk16, Wq16, bv, bq,
                                              WVOT, WQKT, bvwo, bqk);
  // 3) G[h] = x @ WQKT_h^T + bqk_h  (scale 1/16 pre-folded)
  gemm_f16_kernel<false><<<dim3(8, 2, 4), 256, 0, stream>>>(
      xb, 1024, 0, WQKT, 1024, 1048576, 32, bqk, 1024, 1.0f, (void*)G, 1024, 262144);
  // 4) S[h] = G_h @ hist^T  (256^2 core, 256 blocks)
  gemm256_s_kernel<<<dim3(256), 512, 0, stream>>>(G, histb, Sb);
  // 5) softmax: per-dilation Z, merged frame weights, P in place
  softmax_kernel<<<dim3(1024), 256, 0, stream>>>(Sb, dil_w);
  // 6) PH partials = P_h @ hist (256^2 core, split-14 into dead-region chunks)
  gemm256_ph_kernel<<<dim3(224), 512, 0, stream>>>(Sb, histT, ws);
  // 7) reduce 14 chunks -> PHred[q][h*1024+k] f16
  reduce_ph_kernel<<<dim3(1024), 256, 0, stream>>>(ws, PHred);
  // 8) FO partials = PHred @ WVOT^T (split-K 8; scale 1/256)
  gemm_f16_kernel<true><<<dim3(8, 2, 8), 256, 0, stream>>>(
      PHred, 4096, 512, WVOT, 4096, 512, 16, nullptr, 0, 1.0f / 256.0f,
      (void*)oppart, 1024, 262144);
  // 9) 8-way reduce + bo + bv@Wo + residual + layernorm
  ln_kernel<<<dim3(256), 256, 0, stream>>>(x, oppart, bo, bvwo, gamma, beta, (float*)d_out);
}

// Round 7
// 327.440 us; speedup vs baseline: 1.0454x; 1.0454x over previous
//
#include <hip/hip_runtime.h>

// TemporalDilatedAttention on gfx950 — round 13 (R12 resubmit; container
// infra failure gave no signal; depth-3 ledger + chunk aliasing + barrier
// uniformity re-audited, no hazard found).
// vs R11 (PASSED 342us, PH 60.5us): R11's PMC showed PH is HBM-BOUND:
// 195 MB moved (133 fetch vs 64 unique + 57 f32-partial writes) at 3.2 TB/s
// == 60us. Fixes: (1) XCD-pinned split-16 mapping (g = (bid&7) + 8*(slot>>4))
// -> all 16 sharers of a K-group on one XCD L2, fetch ~halves; (2) f16
// partials (PHred is already f16; one extra rounding per chunk, 6x headroom)
// in 16 x 2MB dead regions -> write 57->33 MB, reduce reads 56->32 MB;
// (3) depth-3 counted-vmcnt pipeline (vmcnt(8), 4 bufs) to fill HBM at
// 1 block/CU. S keeps the same core (inherits depth-3).

#define DD    1024
#define TALL  16384

typedef _Float16 half8  __attribute__((ext_vector_type(8)));
typedef _Float16 half4v __attribute__((ext_vector_type(4)));
typedef float    floatx4 __attribute__((ext_vector_type(4)));
typedef unsigned int u32;

// ---------------- workspace layout (bytes), ~132.5 MB ----------------
static const size_t OFF_WOT  = 0;          // 2 MB  Wo^T f16
static const size_t OFF_WV16 = 2097152;    // 2 MB  Wv f16
static const size_t OFF_WK16 = 4194304;    // 2 MB  Wk f16
static const size_t OFF_WQ16 = 6291456;    // 2 MB  Wq f16
static const size_t OFF_XB   = 8388608;    // 0.5 MB x f16
static const size_t OFF_G    = 8912896;    // 2 MB  G[h][q][f] f16
static const size_t OFF_WVOT = 11010048;   // 8 MB  WVOT[j][h*1024+k] f16 (LIVE through FO)
static const size_t OFF_WQKT = 19398656;   // 8 MB  WQKT[h][f][d] f16 (dead after G)
static const size_t OFF_BVWO = 27787264;   // 4 KB  bv@Wo f32
static const size_t OFF_BQK  = 27791360;   // 16 KB bqk[h][f] f32
static const size_t OFF_PHR  = 27807744;   // 2 MB  PHred[q][h*1024+k] f16
static const size_t OFF_OPP  = 29904896;   // 8 MB  FO partials (8 x 256x1024 f32)
static const size_t OFF_HB   = 38293504;   // 32 MB histb (dead after S)
static const size_t OFF_HT   = 71848960;   // 32 MB hist^T f16 [feat][t]
static const size_t OFF_S    = 105403392;  // 32 MB S/P f16 [h][q][t]

// PH f16 partial chunks: 16 x 2 MB over regions dead during launches 6-7.
// g<4: weight cvts [0,8MB)  g in [4,8): WQKT  g in [8,12): OPP (FO writes it
// only AFTER reduce reads, stream-ordered)  g in [12,16): histb (first 8MB).
__device__ __forceinline__ size_t chunk16_off(int g) {
  if (g < 4)  return (size_t)g * 2097152;
  if (g < 8)  return 19398656 + (size_t)(g - 4) * 2097152;
  if (g < 12) return 29904896 + (size_t)(g - 8) * 2097152;
  return 38293504 + (size_t)(g - 12) * 2097152;
}

// ---------------- async global->LDS, 16B per lane ----------------
__device__ __forceinline__ void gl_lds16(const void* g, void* l) {
  __builtin_amdgcn_global_load_lds((const __attribute__((address_space(1))) u32*)g,
                                   (__attribute__((address_space(3))) u32*)l, 16, 0, 0);
}

// ---------------- prep (unchanged) ----------------
__global__ void prep_kernel(const float* __restrict__ Wo, const float* __restrict__ Wv,
                            const float* __restrict__ Wk, const float* __restrict__ Wq,
                            const float* __restrict__ x, const float* __restrict__ hist,
                            _Float16* __restrict__ WoT, _Float16* __restrict__ Wv16,
                            _Float16* __restrict__ Wk16, _Float16* __restrict__ Wq16,
                            _Float16* __restrict__ xb, _Float16* __restrict__ histb,
                            _Float16* __restrict__ histT) {
  int bid = blockIdx.x, tid = threadIdx.x;
  if (bid < 1024) {                        // Wo transpose+cvt
    int k0 = (bid & 31) * 32, n0 = (bid >> 5) * 32;
    __shared__ float t32[32][33];
    int tx = tid & 31, ty = tid >> 5;
#pragma unroll
    for (int i = 0; i < 4; i++) {
      int r = ty + i * 8;
      t32[r][tx] = Wo[(size_t)(k0 + r) * DD + n0 + tx];
    }
    __syncthreads();
#pragma unroll
    for (int i = 0; i < 4; i++) {
      int r = ty + i * 8;
      WoT[(size_t)(n0 + r) * DD + k0 + tx] = (_Float16)t32[tx][r];
    }
  } else if (bid < 4352) {                 // plain cvt
    const float* src; _Float16* dst; size_t i;
    if (bid < 2048)      { src = Wv; dst = Wv16; i = (size_t)(bid - 1024) * 256 + tid; }
    else if (bid < 3072) { src = Wk; dst = Wk16; i = (size_t)(bid - 2048) * 256 + tid; }
    else if (bid < 4096) { src = Wq; dst = Wq16; i = (size_t)(bid - 3072) * 256 + tid; }
    else                 { src = x;  dst = xb;   i = (size_t)(bid - 4096) * 256 + tid; }
    float4 v = ((const float4*)src)[i];
    half4v h = {(_Float16)v.x, (_Float16)v.y, (_Float16)v.z, (_Float16)v.w};
    *(half4v*)(dst + 4 * i) = h;
  } else {                                 // hist dual write
    int tb = bid - 4352;
    int t0 = (tb & 255) * 64, f0 = (tb >> 8) * 64;
    __shared__ _Float16 lt[64][72];
    int r = tid >> 2, c0 = (tid & 3) * 16;
    half8 s0, s1;
#pragma unroll
    for (int i = 0; i < 4; i++) {
      float4 v = *(const float4*)&hist[(size_t)(t0 + r) * 1024 + f0 + c0 + i * 4];
      half4v h = {(_Float16)v.x, (_Float16)v.y, (_Float16)v.z, (_Float16)v.w};
      *(half4v*)&lt[r][c0 + i * 4] = h;
      if (i < 2) { s0[i*4]=h[0]; s0[i*4+1]=h[1]; s0[i*4+2]=h[2]; s0[i*4+3]=h[3]; }
      else { s1[(i-2)*4]=h[0]; s1[(i-2)*4+1]=h[1]; s1[(i-2)*4+2]=h[2]; s1[(i-2)*4+3]=h[3]; }
    }
    *(half8*)&histb[(size_t)(t0 + r) * 1024 + f0 + c0] = s0;
    *(half8*)&histb[(size_t)(t0 + r) * 1024 + f0 + c0 + 8] = s1;
    __syncthreads();
    int fr = tid >> 2, tc0 = (tid & 3) * 16;
    half8 o0, o1;
#pragma unroll
    for (int j = 0; j < 8; j++) { o0[j] = lt[tc0 + j][fr]; o1[j] = lt[tc0 + 8 + j][fr]; }
    *(half8*)&histT[(size_t)(f0 + fr) * TALL + t0 + tc0] = o0;
    *(half8*)&histT[(size_t)(f0 + fr) * TALL + t0 + tc0 + 8] = o1;
  }
}

// ---------------- R9 128x128 core (kept for wpack/G/FO) -------------------
__device__ __forceinline__ void gemm_core(const _Float16* __restrict__ A, size_t lda,
                                          const _Float16* __restrict__ B, size_t ldb,
                                          int kIters, _Float16* As, _Float16* Bs,
                                          int tid, floatx4 acc[4][4]) {
  int lane = tid & 63, w = tid >> 6;
  int l15 = lane & 15, quad = lane >> 4;
  int wm = (w >> 1) * 64, wn = (w & 1) * 64;
  int swz = ((tid & 3) ^ ((tid >> 3) & 3)) * 8;
  int pch = (quad ^ ((l15 >> 1) & 3)) * 8;
  const char* gA0 = (const char*)(A + (size_t)(tid >> 2) * lda + swz);
  const char* gA1 = (const char*)(A + ((size_t)(tid >> 2) + 64) * lda + swz);
  const char* gB0 = (const char*)(B + (size_t)(tid >> 2) * ldb + swz);
  const char* gB1 = (const char*)(B + ((size_t)(tid >> 2) + 64) * ldb + swz);
  _Float16* lA = As + w * 512;
  _Float16* lB = Bs + w * 512;
#define GC_STAGE(buf, k)                                    \
  do {                                                      \
    size_t off_ = (size_t)(k) * 64;                         \
    gl_lds16(gA0 + off_, lA + (buf) * 4096);                \
    gl_lds16(gA1 + off_, lA + (buf) * 4096 + 2048);         \
    gl_lds16(gB0 + off_, lB + (buf) * 4096);                \
    gl_lds16(gB1 + off_, lB + (buf) * 4096 + 2048);         \
  } while (0)
#define GC_STEP(buf, k)                                                       \
  do {                                                                        \
    if ((k) + 1 < kIters) asm volatile("s_waitcnt vmcnt(4)" ::: "memory");    \
    else                  asm volatile("s_waitcnt vmcnt(0)" ::: "memory");    \
    asm volatile("s_barrier" ::: "memory");                                   \
    const _Float16* Ac_ = As + (buf) * 4096;                                  \
    const _Float16* Bc_ = Bs + (buf) * 4096;                                  \
    half8 a_[4];                                                              \
    _Pragma("unroll")                                                         \
    for (int mi = 0; mi < 4; mi++)                                            \
      a_[mi] = *(const half8*)&Ac_[(wm + mi * 16 + l15) * 32 + pch];          \
    _Pragma("unroll")                                                         \
    for (int ni = 0; ni < 4; ni++) {                                          \
      half8 b8_ = *(const half8*)&Bc_[(wn + ni * 16 + l15) * 32 + pch];       \
      _Pragma("unroll")                                                       \
      for (int mi = 0; mi < 4; mi++)                                          \
        acc[mi][ni] = __builtin_amdgcn_mfma_f32_16x16x32_f16(a_[mi], b8_,     \
                                                             acc[mi][ni], 0, 0, 0); \
    }                                                                         \
    asm volatile("s_waitcnt lgkmcnt(0)" ::: "memory");                        \
    asm volatile("s_barrier" ::: "memory");                                   \
    if ((k) + 2 < kIters) GC_STAGE(buf, (k) + 2);                             \
  } while (0)
  GC_STAGE(0, 0);
  GC_STAGE(1, 1);
  for (int kk = 0; kk < kIters; kk += 2) {
    GC_STEP(0, kk);
    GC_STEP(1, kk + 1);
  }
#undef GC_STEP
#undef GC_STAGE
}

// ---------------- 256x256 8-wave BK=32 quad-buffered core, depth-3 --------
// LDS: As/Bs = [4 bufs][256 rows][32 f16] = 64 KB each. Per K-tile: 4
// gl_lds16/thread stages, 12 ds_read_b128/wave, 32 MFMA/wave. Depth-3:
// stages {t, t+1, t+2} outstanding at tile entry -> vmcnt(8) retires t while
// two tiles' loads stay in flight across the barrier (~2 tile-times > HBM
// latency). ST(t+3) overwrites buf (t-1)&3: every wave's ds_reads of it
// completed (tail lgkmcnt(0)) before barrier t, so post-barrier re-stage is
// race-free. Ledger: entry outstanding = 4*min(3, nT-t) -> vmcnt(8/4/0).
__device__ __forceinline__ void gemm256_core(const _Float16* __restrict__ A, size_t lda,
                                             const _Float16* __restrict__ B, size_t ldb,
                                             int nT, _Float16* As, _Float16* Bs,
                                             int tid, floatx4 acc[8][4]) {
  int lane = tid & 63, w = tid >> 6;
  int l15 = lane & 15, quad = lane >> 4;
  int wr = w >> 2, wc = w & 3;             // wave grid 2 (M) x 4 (N)
  int pch = (quad ^ ((l15 >> 1) & 3)) * 8;
  int srow = tid >> 2;                      // 0..127 (round 0 rows)
  int schunk = (tid & 3) ^ ((tid >> 3) & 3);
  const char* gA0 = (const char*)(A + (size_t)srow * lda + schunk * 8);
  const char* gA1 = (const char*)(A + (size_t)(srow + 128) * lda + schunk * 8);
  const char* gB0 = (const char*)(B + (size_t)srow * ldb + schunk * 8);
  const char* gB1 = (const char*)(B + (size_t)(srow + 128) * ldb + schunk * 8);
  _Float16* lA = As + w * 512;              // wave's 1-KB segment per round
  _Float16* lB = Bs + w * 512;
#define ST256(buf, t)                                         \
  do { size_t o_ = (size_t)(t) * 64;                          \
    gl_lds16(gA0 + o_, lA + (buf) * 8192);                    \
    gl_lds16(gA1 + o_, lA + (buf) * 8192 + 4096);             \
    gl_lds16(gB0 + o_, lB + (buf) * 8192);                    \
    gl_lds16(gB1 + o_, lB + (buf) * 8192 + 4096);             \
  } while (0)
  ST256(0, 0);
  if (nT > 1) ST256(1, 1);
  if (nT > 2) ST256(2, 2);
  for (int t = 0; t < nT; ++t) {
    int buf = t & 3;
    if (t + 2 < nT)      asm volatile("s_waitcnt vmcnt(8)" ::: "memory");
    else if (t + 1 < nT) asm volatile("s_waitcnt vmcnt(4)" ::: "memory");
    else                 asm volatile("s_waitcnt vmcnt(0)" ::: "memory");
    asm volatile("s_barrier" ::: "memory");
    if (t + 3 < nT) ST256((t + 3) & 3, t + 3);
    const _Float16* Ac = As + buf * 8192;
    const _Float16* Bc = Bs + buf * 8192;
    half8 b8[4];
#pragma unroll
    for (int ni = 0; ni < 4; ni++)
      b8[ni] = *(const half8*)&Bc[(wc * 64 + ni * 16 + l15) * 32 + pch];
    half8 a8[4];
#pragma unroll
    for (int mi = 0; mi < 4; mi++)
      a8[mi] = *(const half8*)&Ac[(wr * 128 + mi * 16 + l15) * 32 + pch];
    __builtin_amdgcn_s_setprio(1);
#pragma unroll
    for (int mi = 0; mi < 4; mi++)
#pragma unroll
      for (int ni = 0; ni < 4; ni++)
        acc[mi][ni] = __builtin_amdgcn_mfma_f32_16x16x32_f16(a8[mi], b8[ni], acc[mi][ni], 0, 0, 0);
    __builtin_amdgcn_s_setprio(0);
#pragma unroll
    for (int mi = 0; mi < 4; mi++)
      a8[mi] = *(const half8*)&Ac[(wr * 128 + 64 + mi * 16 + l15) * 32 + pch];
    __builtin_amdgcn_s_setprio(1);
#pragma unroll
    for (int mi = 0; mi < 4; mi++)
#pragma unroll
      for (int ni = 0; ni < 4; ni++)
        acc[4 + mi][ni] = __builtin_amdgcn_mfma_f32_16x16x32_f16(a8[mi], b8[ni], acc[4 + mi][ni], 0, 0, 0);
    __builtin_amdgcn_s_setprio(0);
    asm volatile("s_waitcnt lgkmcnt(0)" ::: "memory");
  }
#undef ST256
}

// ---------------- generic single-B GEMM (R9 core) ----------------
template <bool OUTF32>
__launch_bounds__(256, 3)
__global__ void gemm_f16_kernel(const _Float16* __restrict__ A, size_t lda, size_t aoffz,
                                const _Float16* __restrict__ B, size_t ldb, size_t boffz,
                                int kIters, const float* __restrict__ bias, size_t biasoffz,
                                float scale, void* __restrict__ C, size_t ldc, size_t coffz) {
  __shared__ __align__(16) _Float16 As[8192];
  __shared__ __align__(16) _Float16 Bs[8192];
  int tid = threadIdx.x;
  const _Float16* Ab = A + aoffz * blockIdx.z + (size_t)(blockIdx.y * 128) * lda;
  const _Float16* Bb = B + boffz * blockIdx.z + (size_t)(blockIdx.x * 128) * ldb;
  floatx4 acc[4][4];
  floatx4 zero = {0.f, 0.f, 0.f, 0.f};
#pragma unroll
  for (int a = 0; a < 4; a++)
#pragma unroll
    for (int b = 0; b < 4; b++) acc[a][b] = zero;
  gemm_core(Ab, lda, Bb, ldb, kIters, As, Bs, tid, acc);
  int lane = tid & 63, w = tid >> 6;
  int l15 = lane & 15, quad = lane >> 4;
  int wm = (w >> 1) * 64, wn = (w & 1) * 64;
#pragma unroll
  for (int mi = 0; mi < 4; mi++)
#pragma unroll
    for (int ni = 0; ni < 4; ni++) {
      int colg = blockIdx.x * 128 + wn + ni * 16 + l15;
      float bv = bias ? bias[biasoffz * blockIdx.z + colg] : 0.f;
#pragma unroll
      for (int r = 0; r < 4; r++) {
        int rowg = blockIdx.y * 128 + wm + mi * 16 + quad * 4 + r;
        float v = (acc[mi][ni][r] + bv) * scale;
        size_t idx = coffz * blockIdx.z + (size_t)rowg * ldc + colg;
        if (OUTF32) ((float*)C)[idx] = v;
        else ((_Float16*)C)[idx] = (_Float16)v;
      }
    }
}

// ---------------- wpack (unchanged, R9 core) ----------------
__launch_bounds__(256, 3)
__global__ void wpack_kernel(const _Float16* __restrict__ WoT, const _Float16* __restrict__ Wv16,
                             const _Float16* __restrict__ Wk16, const _Float16* __restrict__ Wq16,
                             const float* __restrict__ bv, const float* __restrict__ bq,
                             _Float16* __restrict__ WVOT, _Float16* __restrict__ WQKT,
                             float* __restrict__ bvwo, float* __restrict__ bqk) {
  __shared__ __align__(16) _Float16 As[8192];
  __shared__ __align__(16) _Float16 Bs[8192];
  int bid = blockIdx.x, tid = threadIdx.x;
  if (bid < 512) {
    bool isQK = bid >= 256;
    int g = bid & 255;
    int x = g & 7, y = (g >> 3) & 7, z = g >> 6;
    const _Float16* A = isQK ? Wk16 : WoT;
    const _Float16* B = isQK ? Wq16 : Wv16;
    const _Float16* Ab = A + 256 * z + (size_t)(y * 128) * 1024;
    const _Float16* Bb = B + 256 * z + (size_t)(x * 128) * 1024;
    floatx4 acc[4][4];
    floatx4 zero = {0.f, 0.f, 0.f, 0.f};
#pragma unroll
    for (int a = 0; a < 4; a++)
#pragma unroll
      for (int b = 0; b < 4; b++) acc[a][b] = zero;
    gemm_core(Ab, 1024, Bb, 1024, 8, As, Bs, tid, acc);
    float scale = isQK ? 0.0625f : 1.0f;
    _Float16* C = isQK ? WQKT : WVOT;
    size_t ldc = isQK ? 1024 : 4096;
    size_t zoff = isQK ? (size_t)1048576 * z : (size_t)1024 * z;
    int lane = tid & 63, w = tid >> 6;
    int l15 = lane & 15, quad = lane >> 4;
    int wm = (w >> 1) * 64, wn = (w & 1) * 64;
#pragma unroll
    for (int mi = 0; mi < 4; mi++)
#pragma unroll
      for (int ni = 0; ni < 4; ni++) {
        int col = x * 128 + wn + ni * 16 + l15;
#pragma unroll
        for (int r = 0; r < 4; r++) {
          int row = y * 128 + wm + mi * 16 + quad * 4 + r;
          C[zoff + (size_t)row * ldc + col] = (_Float16)(acc[mi][ni][r] * scale);
        }
      }
  } else if (bid < 516) {
    int j = (bid - 512) * 256 + tid;
    const half8* row = (const half8*)(WoT + (size_t)j * 1024);
    float a = 0.f;
    for (int c = 0; c < 128; c++) {
      half8 w8 = row[c];
#pragma unroll
      for (int e = 0; e < 8; e++) a += bv[c * 8 + e] * (float)w8[e];
    }
    bvwo[j] = a;
  } else {
    int idx = (bid - 516) * 256 + tid;
    int h = idx >> 10, f = idx & 1023;
    const _Float16* row = Wk16 + (size_t)f * 1024 + h * 256;
    float a = 0.f;
    for (int n = 0; n < 256; n++) a += bq[h * 256 + n] * (float)row[n];
    bqk[idx] = a * 0.0625f;
  }
}

// ---------------- S gemm: 256^2 core, 256 blocks (1/CU) -------------------
// bid = h*64 + nt: the 4 h-sharers of a histb nt-strip differ by 64 = 0 mod 8
// -> same XCD L2.
__launch_bounds__(512, 2)
__global__ void gemm256_s_kernel(const _Float16* __restrict__ G, const _Float16* __restrict__ histb,
                                 _Float16* __restrict__ S) {
  __shared__ __align__(16) _Float16 As[32768];
  __shared__ __align__(16) _Float16 Bs[32768];
  int bid = blockIdx.x, tid = threadIdx.x;
  int h = bid >> 6, nt = bid & 63;
  const _Float16* Ab = G + (size_t)h * 262144;
  const _Float16* Bb = histb + (size_t)(nt * 256) * 1024;
  floatx4 acc[8][4];
  floatx4 zero = {0.f, 0.f, 0.f, 0.f};
#pragma unroll
  for (int a = 0; a < 8; a++)
#pragma unroll
    for (int b = 0; b < 4; b++) acc[a][b] = zero;
  gemm256_core(Ab, 1024, Bb, 1024, 32, As, Bs, tid, acc);
  int lane = tid & 63, w = tid >> 6;
  int l15 = lane & 15, quad = lane >> 4;
  int wr = w >> 2, wc = w & 3;
#pragma unroll
  for (int mh = 0; mh < 2; mh++)
#pragma unroll
    for (int mi = 0; mi < 4; mi++)
#pragma unroll
      for (int ni = 0; ni < 4; ni++) {
        int col = nt * 256 + wc * 64 + ni * 16 + l15;
#pragma unroll
        for (int r = 0; r < 4; r++) {
          int row = wr * 128 + mh * 64 + mi * 16 + quad * 4 + r;
          S[(size_t)h * 4194304 + (size_t)row * TALL + col] = (_Float16)acc[mh * 4 + mi][ni][r];
        }
      }
}

// ---------------- softmax (unchanged) -------------------------------------
__global__ void softmax_kernel(_Float16* __restrict__ S, const float* __restrict__ dil_w) {
  int r = blockIdx.x, tid = threadIdx.x;
  _Float16* row = S + (size_t)r * TALL;
  int lane = tid & 63;
  float ef[8][8];
  float es[8];
  __shared__ float Zf[64];
  __shared__ float Zd[4];
  __shared__ float cf[64];
#pragma unroll
  for (int i = 0; i < 8; i++) {
    half8 v = *(const half8*)&row[((size_t)i * 256 + tid) * 8];
    float s = 0.f;
#pragma unroll
    for (int j = 0; j < 8; j++) { float e = __expf((float)v[j]); ef[i][j] = e; s += e; }
#pragma unroll
    for (int off = 1; off <= 16; off <<= 1) s += __shfl_xor(s, off, 64);
    es[i] = s;
  }
  if ((lane & 31) == 0) {
    int half = tid >> 5;
#pragma unroll
    for (int i = 0; i < 8; i++) Zf[i * 8 + half] = es[i];
  }
  __syncthreads();
  if (tid < 4) {
    int step = 1 << (tid + (tid ? 1 : 0));   // 1,4,8,16
    float z = 0.f;
    for (int f = 0; f < 64; f += step) z += Zf[f];
    Zd[tid] = z;
  }
  __syncthreads();
  if (tid < 64) {
    float w0 = dil_w[0], w1 = dil_w[1], w2 = dil_w[2], w3 = dil_w[3];
    float wmx = fmaxf(fmaxf(w0, w1), fmaxf(w2, w3));
    float e0 = __expf(w0 - wmx), e1 = __expf(w1 - wmx), e2 = __expf(w2 - wmx), e3 = __expf(w3 - wmx);
    float wsum = e0 + e1 + e2 + e3;
    float c = (e0 / wsum) / Zd[0];
    if ((tid & 3) == 0) c += (e1 / wsum) / Zd[1];
    if ((tid & 7) == 0) c += (e2 / wsum) / Zd[2];
    if ((tid & 15) == 0) c += (e3 / wsum) / Zd[3];
    cf[tid] = c * 256.0f;   // x256 keeps P normal in f16; /256 folded into FO
  }
  __syncthreads();
#pragma unroll
  for (int i = 0; i < 8; i++) {
    float c = cf[i * 8 + (tid >> 5)];
    half8 o;
#pragma unroll
    for (int j = 0; j < 8; j++) o[j] = (_Float16)(ef[i][j] * c);
    *(half8*)&row[((size_t)i * 256 + tid) * 8] = o;
  }
}

// ---------------- PH gemm: 256^2 core, split-16, XCD-pinned, 256 blocks ---
// 512 K-tiles over 16 uniform groups of 32. Mapping: xcd = bid&7,
// slot = bid>>3 (0..31); g = xcd + 8*(slot>>4); member = slot&15 ->
// h = member>>2, nt = member&3. All 16 sharers of group g live on XCD g&7
// (A-slice shared by 4 nt, B-slice shared by 4 h -> fetched once per XCD).
// Partials in f16 (PHred is f16 anyway; ~sqrt(16) x f16-eps extra error,
// 6x threshold headroom). 16 x 2MB chunks in dead regions.
__launch_bounds__(512, 2)
__global__ void gemm256_ph_kernel(const _Float16* __restrict__ P, const _Float16* __restrict__ histT,
                                  char* __restrict__ ws) {
  __shared__ __align__(16) _Float16 As[32768];
  __shared__ __align__(16) _Float16 Bs[32768];
  int bid = blockIdx.x, tid = threadIdx.x;
  int xcd = bid & 7, slot = bid >> 3;
  int g = xcd + 8 * (slot >> 4);
  int member = slot & 15;
  int h = member >> 2, nt = member & 3;
  const _Float16* Ab = P + (size_t)h * 4194304 + (size_t)g * 1024;
  const _Float16* Bb = histT + (size_t)(nt * 256) * TALL + (size_t)g * 1024;
  floatx4 acc[8][4];
  floatx4 zero = {0.f, 0.f, 0.f, 0.f};
#pragma unroll
  for (int a = 0; a < 8; a++)
#pragma unroll
    for (int b = 0; b < 4; b++) acc[a][b] = zero;
  gemm256_core(Ab, TALL, Bb, TALL, 32, As, Bs, tid, acc);
  _Float16* chunk = (_Float16*)(ws + chunk16_off(g));
  int lane = tid & 63, w = tid >> 6;
  int l15 = lane & 15, quad = lane >> 4;
  int wr = w >> 2, wc = w & 3;
#pragma unroll
  for (int mh = 0; mh < 2; mh++)
#pragma unroll
    for (int mi = 0; mi < 4; mi++)
#pragma unroll
      for (int ni = 0; ni < 4; ni++) {
        int col = h * 1024 + nt * 256 + wc * 64 + ni * 16 + l15;
#pragma unroll
        for (int r = 0; r < 4; r++) {
          int row = wr * 128 + mh * 64 + mi * 16 + quad * 4 + r;
          chunk[(size_t)row * 4096 + col] = (_Float16)acc[mh * 4 + mi][ni][r];
        }
      }
}

// ---------------- reduce 16 f16 PH chunks -> PHred[q][h*1024+k] f16 -------
__global__ void reduce_ph_kernel(const char* __restrict__ ws, _Float16* __restrict__ PHred) {
  size_t e8 = ((size_t)blockIdx.x * 256 + threadIdx.x) * 8;
  float s[8] = {0.f, 0.f, 0.f, 0.f, 0.f, 0.f, 0.f, 0.f};
#pragma unroll
  for (int g = 0; g < 16; g++) {
    const _Float16* p = (const _Float16*)(ws + chunk16_off(g));
    half8 v = *(const half8*)&p[e8];
#pragma unroll
    for (int j = 0; j < 8; j++) s[j] += (float)v[j];
  }
  half8 o;
#pragma unroll
  for (int j = 0; j < 8; j++) o[j] = (_Float16)s[j];
  *(half8*)&PHred[e8] = o;
}

// ---------------- FO 8-way reduce + bo + bv@Wo + residual + layernorm ------
__global__ void ln_kernel(const float* __restrict__ x, const float* __restrict__ part2,
                          const float* __restrict__ bo, const float* __restrict__ bvwo,
                          const float* __restrict__ gamma, const float* __restrict__ beta,
                          float* __restrict__ out) {
  int b = blockIdx.x, t = threadIdx.x;
  __shared__ float red[8];
  float y[4];
  float sum = 0.f, sq = 0.f;
#pragma unroll
  for (int i = 0; i < 4; i++) {
    int j = t + i * 256;
    float v = x[(size_t)b * 1024 + j] + bo[j] + bvwo[j];
#pragma unroll
    for (int z = 0; z < 8; z++) v += part2[(size_t)z * 262144 + (size_t)b * 1024 + j];
    y[i] = v;
    sum += v;
    sq += v * v;
  }
#pragma unroll
  for (int off = 1; off < 64; off <<= 1) {
    sum += __shfl_xor(sum, off, 64);
    sq += __shfl_xor(sq, off, 64);
  }
  int w = t >> 6, lane = t & 63;
  if (lane == 0) { red[w] = sum; red[4 + w] = sq; }
  __syncthreads();
  sum = red[0] + red[1] + red[2] + red[3];
  sq = red[4] + red[5] + red[6] + red[7];
  float mu = sum * (1.f / 1024.f);
  float var = sq * (1.f / 1024.f) - mu * mu;
  float inv = rsqrtf(var + 1e-5f);
#pragma unroll
  for (int i = 0; i < 4; i++) {
    int j = t + i * 256;
    out[(size_t)b * 1024 + j] = (y[i] - mu) * inv * gamma[j] + beta[j];
  }
}

// ---------------- host launch ----------------
extern "C" void kernel_launch(void* const* d_in, const int* in_sizes, int n_in,
                              void* d_out, int out_size, void* d_ws, size_t ws_size,
                              hipStream_t stream) {
  const float* x     = (const float*)d_in[0];
  const float* hist  = (const float*)d_in[1];
  const float* Wq    = (const float*)d_in[2];
  const float* bq    = (const float*)d_in[3];
  const float* Wk    = (const float*)d_in[4];
  // bk (d_in[5]) dropped exactly: softmax shift invariance.
  const float* Wv    = (const float*)d_in[6];
  const float* bv    = (const float*)d_in[7];
  const float* Wo    = (const float*)d_in[8];
  const float* bo    = (const float*)d_in[9];
  const float* dil_w = (const float*)d_in[10];
  const float* gamma = (const float*)d_in[11];
  const float* beta  = (const float*)d_in[12];
  char* ws = (char*)d_ws;

  _Float16* WoT   = (_Float16*)(ws + OFF_WOT);
  _Float16* Wv16  = (_Float16*)(ws + OFF_WV16);
  _Float16* Wk16  = (_Float16*)(ws + OFF_WK16);
  _Float16* Wq16  = (_Float16*)(ws + OFF_WQ16);
  _Float16* xb    = (_Float16*)(ws + OFF_XB);
  _Float16* G     = (_Float16*)(ws + OFF_G);
  _Float16* WVOT  = (_Float16*)(ws + OFF_WVOT);
  _Float16* WQKT  = (_Float16*)(ws + OFF_WQKT);
  float* bvwo     = (float*)(ws + OFF_BVWO);
  float* bqk      = (float*)(ws + OFF_BQK);
  _Float16* PHred = (_Float16*)(ws + OFF_PHR);
  float* oppart   = (float*)(ws + OFF_OPP);
  _Float16* histb = (_Float16*)(ws + OFF_HB);
  _Float16* histT = (_Float16*)(ws + OFF_HT);
  _Float16* Sb    = (_Float16*)(ws + OFF_S);

  // 1) prep: WoT, Wv/Wk/Wq/x cvt, hist -> histb + histT (single hist read)
  prep_kernel<<<dim3(8448), 256, 0, stream>>>(Wo, Wv, Wk, Wq, x, hist,
                                              WoT, Wv16, Wk16, Wq16, xb, histb, histT);
  // 2) wpack: WVOT + WQKT + bvwo + bqk in one launch
  wpack_kernel<<<dim3(532), 256, 0, stream>>>(WoT, Wv16, Wk16, Wq16, bv, bq,
                                              WVOT, WQKT, bvwo, bqk);
  // 3) G[h] = x @ WQKT_h^T + bqk_h  (scale 1/16 pre-folded)
  gemm_f16_kernel<false><<<dim3(8, 2, 4), 256, 0, stream>>>(
      xb, 1024, 0, WQKT, 1024, 1048576, 32, bqk, 1024, 1.0f, (void*)G, 1024, 262144);
  // 4) S[h] = G_h @ hist^T  (256^2 core, 256 blocks)
  gemm256_s_kernel<<<dim3(256), 512, 0, stream>>>(G, histb, Sb);
  // 5) softmax: per-dilation Z, merged frame weights, P in place
  softmax_kernel<<<dim3(1024), 256, 0, stream>>>(Sb, dil_w);
  // 6) PH partials = P_h @ hist (256^2 core, split-16, XCD-pinned, f16 chunks)
  gemm256_ph_kernel<<<dim3(256), 512, 0, stream>>>(Sb, histT, ws);
  // 7) reduce 16 f16 chunks -> PHred[q][h*1024+k] f16
  reduce_ph_kernel<<<dim3(512), 256, 0, stream>>>(ws, PHred);
  // 8) FO partials = PHred @ WVOT^T (split-K 8; scale 1/256)
  gemm_f16_kernel<true><<<dim3(8, 2, 8), 256, 0, stream>>>(
      PHred, 4096, 512, WVOT, 4096, 512, 16, nullptr, 0, 1.0f / 256.0f,
      (void*)oppart, 1024, 262144);
  // 9) 8-way reduce + bo + bv@Wo + residual + layernorm
  ln_kernel<<<dim3(256), 256, 0, stream>>>(x, oppart, bo, bvwo, gamma, beta, (float*)d_out);
}

// Round 8
// 322.817 us; speedup vs baseline: 1.0603x; 1.0143x over previous
//
#include <hip/hip_runtime.h>

// TemporalDilatedAttention on gfx950 — round 14
// vs R13 (PASSED 327us, PH 52us): R13 PMC shows PH traffic FIXED (fetch
// 133->35 MB, write 57->33 MB) but all pipes idle (MFMA 25%, HBM 17%) —
// 660 TF-equiv == the documented 2-phase-structure plateau (m230: 655-682)
// at this exact geometry; 8-phase == 1563. Bank conflicts measured ZERO, so
// the missing lever is the PHASE STRUCTURE alone: gemm256_core compute is
// rebuilt as two m201-style phases per K-tile {ds_read burst, stage-half,
// barrier, lgkmcnt(0), setprio(1) 16-MFMA setprio(0), barrier} on top of
// the UNCHANGED R13 staging/vmcnt/quad-buffer ledger (stage split 2+2,
// same retirement counts). MFMA order per accumulator unchanged ->
// numerics bit-identical. S and PH both inherit.

#define DD    1024
#define TALL  16384

typedef _Float16 half8  __attribute__((ext_vector_type(8)));
typedef _Float16 half4v __attribute__((ext_vector_type(4)));
typedef float    floatx4 __attribute__((ext_vector_type(4)));
typedef unsigned int u32;

// ---------------- workspace layout (bytes), ~132.5 MB ----------------
static const size_t OFF_WOT  = 0;          // 2 MB  Wo^T f16
static const size_t OFF_WV16 = 2097152;    // 2 MB  Wv f16
static const size_t OFF_WK16 = 4194304;    // 2 MB  Wk f16
static const size_t OFF_WQ16 = 6291456;    // 2 MB  Wq f16
static const size_t OFF_XB   = 8388608;    // 0.5 MB x f16
static const size_t OFF_G    = 8912896;    // 2 MB  G[h][q][f] f16
static const size_t OFF_WVOT = 11010048;   // 8 MB  WVOT[j][h*1024+k] f16 (LIVE through FO)
static const size_t OFF_WQKT = 19398656;   // 8 MB  WQKT[h][f][d] f16 (dead after G)
static const size_t OFF_BVWO = 27787264;   // 4 KB  bv@Wo f32
static const size_t OFF_BQK  = 27791360;   // 16 KB bqk[h][f] f32
static const size_t OFF_PHR  = 27807744;   // 2 MB  PHred[q][h*1024+k] f16
static const size_t OFF_OPP  = 29904896;   // 8 MB  FO partials (8 x 256x1024 f32)
static const size_t OFF_HB   = 38293504;   // 32 MB histb (dead after S)
static const size_t OFF_HT   = 71848960;   // 32 MB hist^T f16 [feat][t]
static const size_t OFF_S    = 105403392;  // 32 MB S/P f16 [h][q][t]

// PH f16 partial chunks: 16 x 2 MB over regions dead during launches 6-7.
__device__ __forceinline__ size_t chunk16_off(int g) {
  if (g < 4)  return (size_t)g * 2097152;
  if (g < 8)  return 19398656 + (size_t)(g - 4) * 2097152;
  if (g < 12) return 29904896 + (size_t)(g - 8) * 2097152;
  return 38293504 + (size_t)(g - 12) * 2097152;
}

// ---------------- async global->LDS, 16B per lane ----------------
__device__ __forceinline__ void gl_lds16(const void* g, void* l) {
  __builtin_amdgcn_global_load_lds((const __attribute__((address_space(1))) u32*)g,
                                   (__attribute__((address_space(3))) u32*)l, 16, 0, 0);
}

// ---------------- prep (unchanged) ----------------
__global__ void prep_kernel(const float* __restrict__ Wo, const float* __restrict__ Wv,
                            const float* __restrict__ Wk, const float* __restrict__ Wq,
                            const float* __restrict__ x, const float* __restrict__ hist,
                            _Float16* __restrict__ WoT, _Float16* __restrict__ Wv16,
                            _Float16* __restrict__ Wk16, _Float16* __restrict__ Wq16,
                            _Float16* __restrict__ xb, _Float16* __restrict__ histb,
                            _Float16* __restrict__ histT) {
  int bid = blockIdx.x, tid = threadIdx.x;
  if (bid < 1024) {                        // Wo transpose+cvt
    int k0 = (bid & 31) * 32, n0 = (bid >> 5) * 32;
    __shared__ float t32[32][33];
    int tx = tid & 31, ty = tid >> 5;
#pragma unroll
    for (int i = 0; i < 4; i++) {
      int r = ty + i * 8;
      t32[r][tx] = Wo[(size_t)(k0 + r) * DD + n0 + tx];
    }
    __syncthreads();
#pragma unroll
    for (int i = 0; i < 4; i++) {
      int r = ty + i * 8;
      WoT[(size_t)(n0 + r) * DD + k0 + tx] = (_Float16)t32[tx][r];
    }
  } else if (bid < 4352) {                 // plain cvt
    const float* src; _Float16* dst; size_t i;
    if (bid < 2048)      { src = Wv; dst = Wv16; i = (size_t)(bid - 1024) * 256 + tid; }
    else if (bid < 3072) { src = Wk; dst = Wk16; i = (size_t)(bid - 2048) * 256 + tid; }
    else if (bid < 4096) { src = Wq; dst = Wq16; i = (size_t)(bid - 3072) * 256 + tid; }
    else                 { src = x;  dst = xb;   i = (size_t)(bid - 4096) * 256 + tid; }
    float4 v = ((const float4*)src)[i];
    half4v h = {(_Float16)v.x, (_Float16)v.y, (_Float16)v.z, (_Float16)v.w};
    *(half4v*)(dst + 4 * i) = h;
  } else {                                 // hist dual write
    int tb = bid - 4352;
    int t0 = (tb & 255) * 64, f0 = (tb >> 8) * 64;
    __shared__ _Float16 lt[64][72];
    int r = tid >> 2, c0 = (tid & 3) * 16;
    half8 s0, s1;
#pragma unroll
    for (int i = 0; i < 4; i++) {
      float4 v = *(const float4*)&hist[(size_t)(t0 + r) * 1024 + f0 + c0 + i * 4];
      half4v h = {(_Float16)v.x, (_Float16)v.y, (_Float16)v.z, (_Float16)v.w};
      *(half4v*)&lt[r][c0 + i * 4] = h;
      if (i < 2) { s0[i*4]=h[0]; s0[i*4+1]=h[1]; s0[i*4+2]=h[2]; s0[i*4+3]=h[3]; }
      else { s1[(i-2)*4]=h[0]; s1[(i-2)*4+1]=h[1]; s1[(i-2)*4+2]=h[2]; s1[(i-2)*4+3]=h[3]; }
    }
    *(half8*)&histb[(size_t)(t0 + r) * 1024 + f0 + c0] = s0;
    *(half8*)&histb[(size_t)(t0 + r) * 1024 + f0 + c0 + 8] = s1;
    __syncthreads();
    int fr = tid >> 2, tc0 = (tid & 3) * 16;
    half8 o0, o1;
#pragma unroll
    for (int j = 0; j < 8; j++) { o0[j] = lt[tc0 + j][fr]; o1[j] = lt[tc0 + 8 + j][fr]; }
    *(half8*)&histT[(size_t)(f0 + fr) * TALL + t0 + tc0] = o0;
    *(half8*)&histT[(size_t)(f0 + fr) * TALL + t0 + tc0 + 8] = o1;
  }
}

// ---------------- R9 128x128 core (kept for wpack/G/FO) -------------------
__device__ __forceinline__ void gemm_core(const _Float16* __restrict__ A, size_t lda,
                                          const _Float16* __restrict__ B, size_t ldb,
                                          int kIters, _Float16* As, _Float16* Bs,
                                          int tid, floatx4 acc[4][4]) {
  int lane = tid & 63, w = tid >> 6;
  int l15 = lane & 15, quad = lane >> 4;
  int wm = (w >> 1) * 64, wn = (w & 1) * 64;
  int swz = ((tid & 3) ^ ((tid >> 3) & 3)) * 8;
  int pch = (quad ^ ((l15 >> 1) & 3)) * 8;
  const char* gA0 = (const char*)(A + (size_t)(tid >> 2) * lda + swz);
  const char* gA1 = (const char*)(A + ((size_t)(tid >> 2) + 64) * lda + swz);
  const char* gB0 = (const char*)(B + (size_t)(tid >> 2) * ldb + swz);
  const char* gB1 = (const char*)(B + ((size_t)(tid >> 2) + 64) * ldb + swz);
  _Float16* lA = As + w * 512;
  _Float16* lB = Bs + w * 512;
#define GC_STAGE(buf, k)                                    \
  do {                                                      \
    size_t off_ = (size_t)(k) * 64;                         \
    gl_lds16(gA0 + off_, lA + (buf) * 4096);                \
    gl_lds16(gA1 + off_, lA + (buf) * 4096 + 2048);         \
    gl_lds16(gB0 + off_, lB + (buf) * 4096);                \
    gl_lds16(gB1 + off_, lB + (buf) * 4096 + 2048);         \
  } while (0)
#define GC_STEP(buf, k)                                                       \
  do {                                                                        \
    if ((k) + 1 < kIters) asm volatile("s_waitcnt vmcnt(4)" ::: "memory");    \
    else                  asm volatile("s_waitcnt vmcnt(0)" ::: "memory");    \
    asm volatile("s_barrier" ::: "memory");                                   \
    const _Float16* Ac_ = As + (buf) * 4096;                                  \
    const _Float16* Bc_ = Bs + (buf) * 4096;                                  \
    half8 a_[4];                                                              \
    _Pragma("unroll")                                                         \
    for (int mi = 0; mi < 4; mi++)                                            \
      a_[mi] = *(const half8*)&Ac_[(wm + mi * 16 + l15) * 32 + pch];          \
    _Pragma("unroll")                                                         \
    for (int ni = 0; ni < 4; ni++) {                                          \
      half8 b8_ = *(const half8*)&Bc_[(wn + ni * 16 + l15) * 32 + pch];       \
      _Pragma("unroll")                                                       \
      for (int mi = 0; mi < 4; mi++)                                          \
        acc[mi][ni] = __builtin_amdgcn_mfma_f32_16x16x32_f16(a_[mi], b8_,     \
                                                             acc[mi][ni], 0, 0, 0); \
    }                                                                         \
    asm volatile("s_waitcnt lgkmcnt(0)" ::: "memory");                        \
    asm volatile("s_barrier" ::: "memory");                                   \
    if ((k) + 2 < kIters) GC_STAGE(buf, (k) + 2);                             \
  } while (0)
  GC_STAGE(0, 0);
  GC_STAGE(1, 1);
  for (int kk = 0; kk < kIters; kk += 2) {
    GC_STEP(0, kk);
    GC_STEP(1, kk + 1);
  }
#undef GC_STEP
#undef GC_STAGE
}

// ---------------- 256x256 8-wave BK=32 core, phase-structured -------------
// R13 staging/ledger UNCHANGED: 4 bufs, depth-3, stage split 2(A)+2(B) per
// tile, vmcnt(8/4/0) at tile entry, barrier -> buf collectively complete.
// NEW (m201 T3): per tile, TWO phases, each {ds_read burst issued, stage
// half issued, s_barrier, lgkmcnt(0), setprio(1) 16 MFMA setprio(0),
// s_barrier}. Reads' latency drains during the barrier; MFMA clusters of
// all 8 waves align (setprio has role-split to arbitrate); LDS-read bursts
// and MFMA bursts serialize cleanly -> MfmaUtil ceiling ~ MFMA/(MFMA+LDS)
// ~ 53% (m201's 62% = same formula at BK=64).
// WAR: stage(t+3)->buf (t-1)&3; every wave drained its reads of that buf at
// its tile-(t-1) phase-2 lgkmcnt(0), before the tile-t entry barrier.
__device__ __forceinline__ void gemm256_core(const _Float16* __restrict__ A, size_t lda,
                                             const _Float16* __restrict__ B, size_t ldb,
                                             int nT, _Float16* As, _Float16* Bs,
                                             int tid, floatx4 acc[8][4]) {
  int lane = tid & 63, w = tid >> 6;
  int l15 = lane & 15, quad = lane >> 4;
  int wr = w >> 2, wc = w & 3;             // wave grid 2 (M) x 4 (N)
  int pch = (quad ^ ((l15 >> 1) & 3)) * 8;
  int srow = tid >> 2;                      // 0..127 (round 0 rows)
  int schunk = (tid & 3) ^ ((tid >> 3) & 3);
  const char* gA0 = (const char*)(A + (size_t)srow * lda + schunk * 8);
  const char* gA1 = (const char*)(A + (size_t)(srow + 128) * lda + schunk * 8);
  const char* gB0 = (const char*)(B + (size_t)srow * ldb + schunk * 8);
  const char* gB1 = (const char*)(B + (size_t)(srow + 128) * ldb + schunk * 8);
  _Float16* lA = As + w * 512;              // wave's 1-KB segment per round
  _Float16* lB = Bs + w * 512;
#define STA256(buf, t)                                        \
  do { size_t o_ = (size_t)(t) * 64;                          \
    gl_lds16(gA0 + o_, lA + (buf) * 8192);                    \
    gl_lds16(gA1 + o_, lA + (buf) * 8192 + 4096);             \
  } while (0)
#define STB256(buf, t)                                        \
  do { size_t o_ = (size_t)(t) * 64;                          \
    gl_lds16(gB0 + o_, lB + (buf) * 8192);                    \
    gl_lds16(gB1 + o_, lB + (buf) * 8192 + 4096);             \
  } while (0)
  STA256(0, 0); STB256(0, 0);
  if (nT > 1) { STA256(1, 1); STB256(1, 1); }
  if (nT > 2) { STA256(2, 2); STB256(2, 2); }
  for (int t = 0; t < nT; ++t) {
    int buf = t & 3;
    if (t + 2 < nT)      asm volatile("s_waitcnt vmcnt(8)" ::: "memory");
    else if (t + 1 < nT) asm volatile("s_waitcnt vmcnt(4)" ::: "memory");
    else                 asm volatile("s_waitcnt vmcnt(0)" ::: "memory");
    asm volatile("s_barrier" ::: "memory");
    const _Float16* Ac = As + buf * 8192;
    const _Float16* Bc = Bs + buf * 8192;
    // ---- phase 1: read B frags + A-low, stage A(t+3), MFMA mi0-3 ----
    half8 b8[4], a8[4];
#pragma unroll
    for (int ni = 0; ni < 4; ni++)
      b8[ni] = *(const half8*)&Bc[(wc * 64 + ni * 16 + l15) * 32 + pch];
#pragma unroll
    for (int mi = 0; mi < 4; mi++)
      a8[mi] = *(const half8*)&Ac[(wr * 128 + mi * 16 + l15) * 32 + pch];
    if (t + 3 < nT) STA256((t + 3) & 3, t + 3);
    asm volatile("s_barrier" ::: "memory");
    asm volatile("s_waitcnt lgkmcnt(0)" ::: "memory");
    __builtin_amdgcn_s_setprio(1);
#pragma unroll
    for (int mi = 0; mi < 4; mi++)
#pragma unroll
      for (int ni = 0; ni < 4; ni++)
        acc[mi][ni] = __builtin_amdgcn_mfma_f32_16x16x32_f16(a8[mi], b8[ni], acc[mi][ni], 0, 0, 0);
    __builtin_amdgcn_s_setprio(0);
    asm volatile("s_barrier" ::: "memory");
    // ---- phase 2: read A-high, stage B(t+3), MFMA mi4-7 ----
#pragma unroll
    for (int mi = 0; mi < 4; mi++)
      a8[mi] = *(const half8*)&Ac[(wr * 128 + 64 + mi * 16 + l15) * 32 + pch];
    if (t + 3 < nT) STB256((t + 3) & 3, t + 3);
    asm volatile("s_barrier" ::: "memory");
    asm volatile("s_waitcnt lgkmcnt(0)" ::: "memory");
    __builtin_amdgcn_s_setprio(1);
#pragma unroll
    for (int mi = 0; mi < 4; mi++)
#pragma unroll
      for (int ni = 0; ni < 4; ni++)
        acc[4 + mi][ni] = __builtin_amdgcn_mfma_f32_16x16x32_f16(a8[mi], b8[ni], acc[4 + mi][ni], 0, 0, 0);
    __builtin_amdgcn_s_setprio(0);
    asm volatile("s_barrier" ::: "memory");
  }
#undef STA256
#undef STB256
}

// ---------------- generic single-B GEMM (R9 core) ----------------
template <bool OUTF32>
__launch_bounds__(256, 3)
__global__ void gemm_f16_kernel(const _Float16* __restrict__ A, size_t lda, size_t aoffz,
                                const _Float16* __restrict__ B, size_t ldb, size_t boffz,
                                int kIters, const float* __restrict__ bias, size_t biasoffz,
                                float scale, void* __restrict__ C, size_t ldc, size_t coffz) {
  __shared__ __align__(16) _Float16 As[8192];
  __shared__ __align__(16) _Float16 Bs[8192];
  int tid = threadIdx.x;
  const _Float16* Ab = A + aoffz * blockIdx.z + (size_t)(blockIdx.y * 128) * lda;
  const _Float16* Bb = B + boffz * blockIdx.z + (size_t)(blockIdx.x * 128) * ldb;
  floatx4 acc[4][4];
  floatx4 zero = {0.f, 0.f, 0.f, 0.f};
#pragma unroll
  for (int a = 0; a < 4; a++)
#pragma unroll
    for (int b = 0; b < 4; b++) acc[a][b] = zero;
  gemm_core(Ab, lda, Bb, ldb, kIters, As, Bs, tid, acc);
  int lane = tid & 63, w = tid >> 6;
  int l15 = lane & 15, quad = lane >> 4;
  int wm = (w >> 1) * 64, wn = (w & 1) * 64;
#pragma unroll
  for (int mi = 0; mi < 4; mi++)
#pragma unroll
    for (int ni = 0; ni < 4; ni++) {
      int colg = blockIdx.x * 128 + wn + ni * 16 + l15;
      float bv = bias ? bias[biasoffz * blockIdx.z + colg] : 0.f;
#pragma unroll
      for (int r = 0; r < 4; r++) {
        int rowg = blockIdx.y * 128 + wm + mi * 16 + quad * 4 + r;
        float v = (acc[mi][ni][r] + bv) * scale;
        size_t idx = coffz * blockIdx.z + (size_t)rowg * ldc + colg;
        if (OUTF32) ((float*)C)[idx] = v;
        else ((_Float16*)C)[idx] = (_Float16)v;
      }
    }
}

// ---------------- wpack (unchanged, R9 core) ----------------
__launch_bounds__(256, 3)
__global__ void wpack_kernel(const _Float16* __restrict__ WoT, const _Float16* __restrict__ Wv16,
                             const _Float16* __restrict__ Wk16, const _Float16* __restrict__ Wq16,
                             const float* __restrict__ bv, const float* __restrict__ bq,
                             _Float16* __restrict__ WVOT, _Float16* __restrict__ WQKT,
                             float* __restrict__ bvwo, float* __restrict__ bqk) {
  __shared__ __align__(16) _Float16 As[8192];
  __shared__ __align__(16) _Float16 Bs[8192];
  int bid = blockIdx.x, tid = threadIdx.x;
  if (bid < 512) {
    bool isQK = bid >= 256;
    int g = bid & 255;
    int x = g & 7, y = (g >> 3) & 7, z = g >> 6;
    const _Float16* A = isQK ? Wk16 : WoT;
    const _Float16* B = isQK ? Wq16 : Wv16;
    const _Float16* Ab = A + 256 * z + (size_t)(y * 128) * 1024;
    const _Float16* Bb = B + 256 * z + (size_t)(x * 128) * 1024;
    floatx4 acc[4][4];
    floatx4 zero = {0.f, 0.f, 0.f, 0.f};
#pragma unroll
    for (int a = 0; a < 4; a++)
#pragma unroll
      for (int b = 0; b < 4; b++) acc[a][b] = zero;
    gemm_core(Ab, 1024, Bb, 1024, 8, As, Bs, tid, acc);
    float scale = isQK ? 0.0625f : 1.0f;
    _Float16* C = isQK ? WQKT : WVOT;
    size_t ldc = isQK ? 1024 : 4096;
    size_t zoff = isQK ? (size_t)1048576 * z : (size_t)1024 * z;
    int lane = tid & 63, w = tid >> 6;
    int l15 = lane & 15, quad = lane >> 4;
    int wm = (w >> 1) * 64, wn = (w & 1) * 64;
#pragma unroll
    for (int mi = 0; mi < 4; mi++)
#pragma unroll
      for (int ni = 0; ni < 4; ni++) {
        int col = x * 128 + wn + ni * 16 + l15;
#pragma unroll
        for (int r = 0; r < 4; r++) {
          int row = y * 128 + wm + mi * 16 + quad * 4 + r;
          C[zoff + (size_t)row * ldc + col] = (_Float16)(acc[mi][ni][r] * scale);
        }
      }
  } else if (bid < 516) {
    int j = (bid - 512) * 256 + tid;
    const half8* row = (const half8*)(WoT + (size_t)j * 1024);
    float a = 0.f;
    for (int c = 0; c < 128; c++) {
      half8 w8 = row[c];
#pragma unroll
      for (int e = 0; e < 8; e++) a += bv[c * 8 + e] * (float)w8[e];
    }
    bvwo[j] = a;
  } else {
    int idx = (bid - 516) * 256 + tid;
    int h = idx >> 10, f = idx & 1023;
    const _Float16* row = Wk16 + (size_t)f * 1024 + h * 256;
    float a = 0.f;
    for (int n = 0; n < 256; n++) a += bq[h * 256 + n] * (float)row[n];
    bqk[idx] = a * 0.0625f;
  }
}

// ---------------- S gemm: 256^2 core, 256 blocks (1/CU) -------------------
__launch_bounds__(512, 2)
__global__ void gemm256_s_kernel(const _Float16* __restrict__ G, const _Float16* __restrict__ histb,
                                 _Float16* __restrict__ S) {
  __shared__ __align__(16) _Float16 As[32768];
  __shared__ __align__(16) _Float16 Bs[32768];
  int bid = blockIdx.x, tid = threadIdx.x;
  int h = bid >> 6, nt = bid & 63;
  const _Float16* Ab = G + (size_t)h * 262144;
  const _Float16* Bb = histb + (size_t)(nt * 256) * 1024;
  floatx4 acc[8][4];
  floatx4 zero = {0.f, 0.f, 0.f, 0.f};
#pragma unroll
  for (int a = 0; a < 8; a++)
#pragma unroll
    for (int b = 0; b < 4; b++) acc[a][b] = zero;
  gemm256_core(Ab, 1024, Bb, 1024, 32, As, Bs, tid, acc);
  int lane = tid & 63, w = tid >> 6;
  int l15 = lane & 15, quad = lane >> 4;
  int wr = w >> 2, wc = w & 3;
#pragma unroll
  for (int mh = 0; mh < 2; mh++)
#pragma unroll
    for (int mi = 0; mi < 4; mi++)
#pragma unroll
      for (int ni = 0; ni < 4; ni++) {
        int col = nt * 256 + wc * 64 + ni * 16 + l15;
#pragma unroll
        for (int r = 0; r < 4; r++) {
          int row = wr * 128 + mh * 64 + mi * 16 + quad * 4 + r;
          S[(size_t)h * 4194304 + (size_t)row * TALL + col] = (_Float16)acc[mh * 4 + mi][ni][r];
        }
      }
}

// ---------------- softmax (unchanged) -------------------------------------
__global__ void softmax_kernel(_Float16* __restrict__ S, const float* __restrict__ dil_w) {
  int r = blockIdx.x, tid = threadIdx.x;
  _Float16* row = S + (size_t)r * TALL;
  int lane = tid & 63;
  float ef[8][8];
  float es[8];
  __shared__ float Zf[64];
  __shared__ float Zd[4];
  __shared__ float cf[64];
#pragma unroll
  for (int i = 0; i < 8; i++) {
    half8 v = *(const half8*)&row[((size_t)i * 256 + tid) * 8];
    float s = 0.f;
#pragma unroll
    for (int j = 0; j < 8; j++) { float e = __expf((float)v[j]); ef[i][j] = e; s += e; }
#pragma unroll
    for (int off = 1; off <= 16; off <<= 1) s += __shfl_xor(s, off, 64);
    es[i] = s;
  }
  if ((lane & 31) == 0) {
    int half = tid >> 5;
#pragma unroll
    for (int i = 0; i < 8; i++) Zf[i * 8 + half] = es[i];
  }
  __syncthreads();
  if (tid < 4) {
    int step = 1 << (tid + (tid ? 1 : 0));   // 1,4,8,16
    float z = 0.f;
    for (int f = 0; f < 64; f += step) z += Zf[f];
    Zd[tid] = z;
  }
  __syncthreads();
  if (tid < 64) {
    float w0 = dil_w[0], w1 = dil_w[1], w2 = dil_w[2], w3 = dil_w[3];
    float wmx = fmaxf(fmaxf(w0, w1), fmaxf(w2, w3));
    float e0 = __expf(w0 - wmx), e1 = __expf(w1 - wmx), e2 = __expf(w2 - wmx), e3 = __expf(w3 - wmx);
    float wsum = e0 + e1 + e2 + e3;
    float c = (e0 / wsum) / Zd[0];
    if ((tid & 3) == 0) c += (e1 / wsum) / Zd[1];
    if ((tid & 7) == 0) c += (e2 / wsum) / Zd[2];
    if ((tid & 15) == 0) c += (e3 / wsum) / Zd[3];
    cf[tid] = c * 256.0f;   // x256 keeps P normal in f16; /256 folded into FO
  }
  __syncthreads();
#pragma unroll
  for (int i = 0; i < 8; i++) {
    float c = cf[i * 8 + (tid >> 5)];
    half8 o;
#pragma unroll
    for (int j = 0; j < 8; j++) o[j] = (_Float16)(ef[i][j] * c);
    *(half8*)&row[((size_t)i * 256 + tid) * 8] = o;
  }
}

// ---------------- PH gemm: 256^2 core, split-16, XCD-pinned, 256 blocks ---
__launch_bounds__(512, 2)
__global__ void gemm256_ph_kernel(const _Float16* __restrict__ P, const _Float16* __restrict__ histT,
                                  char* __restrict__ ws) {
  __shared__ __align__(16) _Float16 As[32768];
  __shared__ __align__(16) _Float16 Bs[32768];
  int bid = blockIdx.x, tid = threadIdx.x;
  int xcd = bid & 7, slot = bid >> 3;
  int g = xcd + 8 * (slot >> 4);
  int member = slot & 15;
  int h = member >> 2, nt = member & 3;
  const _Float16* Ab = P + (size_t)h * 4194304 + (size_t)g * 1024;
  const _Float16* Bb = histT + (size_t)(nt * 256) * TALL + (size_t)g * 1024;
  floatx4 acc[8][4];
  floatx4 zero = {0.f, 0.f, 0.f, 0.f};
#pragma unroll
  for (int a = 0; a < 8; a++)
#pragma unroll
    for (int b = 0; b < 4; b++) acc[a][b] = zero;
  gemm256_core(Ab, TALL, Bb, TALL, 32, As, Bs, tid, acc);
  _Float16* chunk = (_Float16*)(ws + chunk16_off(g));
  int lane = tid & 63, w = tid >> 6;
  int l15 = lane & 15, quad = lane >> 4;
  int wr = w >> 2, wc = w & 3;
#pragma unroll
  for (int mh = 0; mh < 2; mh++)
#pragma unroll
    for (int mi = 0; mi < 4; mi++)
#pragma unroll
      for (int ni = 0; ni < 4; ni++) {
        int col = h * 1024 + nt * 256 + wc * 64 + ni * 16 + l15;
#pragma unroll
        for (int r = 0; r < 4; r++) {
          int row = wr * 128 + mh * 64 + mi * 16 + quad * 4 + r;
          chunk[(size_t)row * 4096 + col] = (_Float16)acc[mh * 4 + mi][ni][r];
        }
      }
}

// ---------------- reduce 16 f16 PH chunks -> PHred[q][h*1024+k] f16 -------
__global__ void reduce_ph_kernel(const char* __restrict__ ws, _Float16* __restrict__ PHred) {
  size_t e8 = ((size_t)blockIdx.x * 256 + threadIdx.x) * 8;
  float s[8] = {0.f, 0.f, 0.f, 0.f, 0.f, 0.f, 0.f, 0.f};
#pragma unroll
  for (int g = 0; g < 16; g++) {
    const _Float16* p = (const _Float16*)(ws + chunk16_off(g));
    half8 v = *(const half8*)&p[e8];
#pragma unroll
    for (int j = 0; j < 8; j++) s[j] += (float)v[j];
  }
  half8 o;
#pragma unroll
  for (int j = 0; j < 8; j++) o[j] = (_Float16)s[j];
  *(half8*)&PHred[e8] = o;
}

// ---------------- FO 8-way reduce + bo + bv@Wo + residual + layernorm ------
__global__ void ln_kernel(const float* __restrict__ x, const float* __restrict__ part2,
                          const float* __restrict__ bo, const float* __restrict__ bvwo,
                          const float* __restrict__ gamma, const float* __restrict__ beta,
                          float* __restrict__ out) {
  int b = blockIdx.x, t = threadIdx.x;
  __shared__ float red[8];
  float y[4];
  float sum = 0.f, sq = 0.f;
#pragma unroll
  for (int i = 0; i < 4; i++) {
    int j = t + i * 256;
    float v = x[(size_t)b * 1024 + j] + bo[j] + bvwo[j];
#pragma unroll
    for (int z = 0; z < 8; z++) v += part2[(size_t)z * 262144 + (size_t)b * 1024 + j];
    y[i] = v;
    sum += v;
    sq += v * v;
  }
#pragma unroll
  for (int off = 1; off < 64; off <<= 1) {
    sum += __shfl_xor(sum, off, 64);
    sq += __shfl_xor(sq, off, 64);
  }
  int w = t >> 6, lane = t & 63;
  if (lane == 0) { red[w] = sum; red[4 + w] = sq; }
  __syncthreads();
  sum = red[0] + red[1] + red[2] + red[3];
  sq = red[4] + red[5] + red[6] + red[7];
  float mu = sum * (1.f / 1024.f);
  float var = sq * (1.f / 1024.f) - mu * mu;
  float inv = rsqrtf(var + 1e-5f);
#pragma unroll
  for (int i = 0; i < 4; i++) {
    int j = t + i * 256;
    out[(size_t)b * 1024 + j] = (y[i] - mu) * inv * gamma[j] + beta[j];
  }
}

// ---------------- host launch ----------------
extern "C" void kernel_launch(void* const* d_in, const int* in_sizes, int n_in,
                              void* d_out, int out_size, void* d_ws, size_t ws_size,
                              hipStream_t stream) {
  const float* x     = (const float*)d_in[0];
  const float* hist  = (const float*)d_in[1];
  const float* Wq    = (const float*)d_in[2];
  const float* bq    = (const float*)d_in[3];
  const float* Wk    = (const float*)d_in[4];
  // bk (d_in[5]) dropped exactly: softmax shift invariance.
  const float* Wv    = (const float*)d_in[6];
  const float* bv    = (const float*)d_in[7];
  const float* Wo    = (const float*)d_in[8];
  const float* bo    = (const float*)d_in[9];
  const float* dil_w = (const float*)d_in[10];
  const float* gamma = (const float*)d_in[11];
  const float* beta  = (const float*)d_in[12];
  char* ws = (char*)d_ws;

  _Float16* WoT   = (_Float16*)(ws + OFF_WOT);
  _Float16* Wv16  = (_Float16*)(ws + OFF_WV16);
  _Float16* Wk16  = (_Float16*)(ws + OFF_WK16);
  _Float16* Wq16  = (_Float16*)(ws + OFF_WQ16);
  _Float16* xb    = (_Float16*)(ws + OFF_XB);
  _Float16* G     = (_Float16*)(ws + OFF_G);
  _Float16* WVOT  = (_Float16*)(ws + OFF_WVOT);
  _Float16* WQKT  = (_Float16*)(ws + OFF_WQKT);
  float* bvwo     = (float*)(ws + OFF_BVWO);
  float* bqk      = (float*)(ws + OFF_BQK);
  _Float16* PHred = (_Float16*)(ws + OFF_PHR);
  float* oppart   = (float*)(ws + OFF_OPP);
  _Float16* histb = (_Float16*)(ws + OFF_HB);
  _Float16* histT = (_Float16*)(ws + OFF_HT);
  _Float16* Sb    = (_Float16*)(ws + OFF_S);

  // 1) prep: WoT, Wv/Wk/Wq/x cvt, hist -> histb + histT (single hist read)
  prep_kernel<<<dim3(8448), 256, 0, stream>>>(Wo, Wv, Wk, Wq, x, hist,
                                              WoT, Wv16, Wk16, Wq16, xb, histb, histT);
  // 2) wpack: WVOT + WQKT + bvwo + bqk in one launch
  wpack_kernel<<<dim3(532), 256, 0, stream>>>(WoT, Wv16, Wk16, Wq16, bv, bq,
                                              WVOT, WQKT, bvwo, bqk);
  // 3) G[h] = x @ WQKT_h^T + bqk_h  (scale 1/16 pre-folded)
  gemm_f16_kernel<false><<<dim3(8, 2, 4), 256, 0, stream>>>(
      xb, 1024, 0, WQKT, 1024, 1048576, 32, bqk, 1024, 1.0f, (void*)G, 1024, 262144);
  // 4) S[h] = G_h @ hist^T  (256^2 phase-structured core, 256 blocks)
  gemm256_s_kernel<<<dim3(256), 512, 0, stream>>>(G, histb, Sb);
  // 5) softmax: per-dilation Z, merged frame weights, P in place
  softmax_kernel<<<dim3(1024), 256, 0, stream>>>(Sb, dil_w);
  // 6) PH partials = P_h @ hist (256^2 phase-structured core, split-16)
  gemm256_ph_kernel<<<dim3(256), 512, 0, stream>>>(Sb, histT, ws);
  // 7) reduce 16 f16 chunks -> PHred[q][h*1024+k] f16
  reduce_ph_kernel<<<dim3(512), 256, 0, stream>>>(ws, PHred);
  // 8) FO partials = PHred @ WVOT^T (split-K 8; scale 1/256)
  gemm_f16_kernel<true><<<dim3(8, 2, 8), 256, 0, stream>>>(
      PHred, 4096, 512, WVOT, 4096, 512, 16, nullptr, 0, 1.0f / 256.0f,
      (void*)oppart, 1024, 262144);
  // 9) 8-way reduce + bo + bv@Wo + residual + layernorm
  ln_kernel<<<dim3(256), 256, 0, stream>>>(x, oppart, bo, bvwo, gamma, beta, (float*)d_out);
}